// Round 1
// baseline (688.792 us; speedup 1.0000x reference)
//
#include <hip/hip_runtime.h>
#include <hip/hip_bf16.h>

#define SEQ   2048
#define DIM   4096
#define NH    32
#define NKV   8
#define HD    128
#define KVDIM 1024
#define SCALE 0.08838834764831845f

typedef __attribute__((ext_vector_type(8))) short bf16x8;
typedef __attribute__((ext_vector_type(4))) float f32x4;

__device__ __forceinline__ ushort f2bf(float f) {  // RTN fp32 -> bf16 bits
  __hip_bfloat16 h = __float2bfloat16(f);
  return *reinterpret_cast<ushort*>(&h);
}

// async global->LDS, 16B per lane; LDS dest = wave-uniform base + lane*16
typedef const __attribute__((address_space(1))) uint* gas_ptr;
typedef __attribute__((address_space(3))) uint* las_ptr;
__device__ __forceinline__ void async16(const ushort* g, ushort* l) {
  __builtin_amdgcn_global_load_lds((gas_ptr)g, (las_ptr)l, 16, 0, 0);
}

// DPP 16-lane-group butterfly reductions (VALU pipe, not LDS)
template <int CTRL>
__device__ __forceinline__ float dppf(float x) {
  return __int_as_float(__builtin_amdgcn_update_dpp(
      0, __float_as_int(x), CTRL, 0xf, 0xf, false));
}
__device__ __forceinline__ float red16_max(float x) {
  x = fmaxf(x, dppf<0xB1>(x));    // quad_perm [1,0,3,2]  (xor 1)
  x = fmaxf(x, dppf<0x4E>(x));    // quad_perm [2,3,0,1]  (xor 2)
  x = fmaxf(x, dppf<0x124>(x));   // row_ror:4
  x = fmaxf(x, dppf<0x128>(x));   // row_ror:8
  return x;
}
__device__ __forceinline__ float red16_sum(float x) {
  x += dppf<0xB1>(x);
  x += dppf<0x4E>(x);
  x += dppf<0x124>(x);
  x += dppf<0x128>(x);
  return x;
}

// ---------------- fp32 -> bf16 elementwise (x) --------------------------------
__global__ __launch_bounds__(256) void convert_f32_bf16(
    const float* __restrict__ in, ushort* __restrict__ out)
{
  int i = (blockIdx.x * 256 + threadIdx.x) * 8;
  float4 a = *(const float4*)(in + i);
  float4 b = *(const float4*)(in + i + 4);
  uint4 u;
  u.x = (uint)f2bf(a.x) | ((uint)f2bf(a.y) << 16);
  u.y = (uint)f2bf(a.z) | ((uint)f2bf(a.w) << 16);
  u.z = (uint)f2bf(b.x) | ((uint)f2bf(b.y) << 16);
  u.w = (uint)f2bf(b.z) | ((uint)f2bf(b.w) << 16);
  *(uint4*)(out + i) = u;
}

// ---------------- W[K][N] fp32 -> WT[N][K] bf16 (32x32 LDS tiles) -------------
__global__ __launch_bounds__(256) void transpose_w(
    const float* __restrict__ W, ushort* __restrict__ WT, int K, int N)
{
  __shared__ float t[32][33];
  const int k0 = blockIdx.y * 32, n0 = blockIdx.x * 32;
  const int tid = threadIdx.x;
  {
    int r = tid >> 3, c0 = (tid & 7) * 4;
    float4 v = *(const float4*)(W + (size_t)(k0 + r) * N + n0 + c0);
    t[r][c0] = v.x; t[r][c0 + 1] = v.y; t[r][c0 + 2] = v.z; t[r][c0 + 3] = v.w;
  }
  __syncthreads();
  {
    int n = tid >> 3, kc = (tid & 7) * 4;
    ushort4 u;
    u.x = f2bf(t[kc + 0][n]); u.y = f2bf(t[kc + 1][n]);
    u.z = f2bf(t[kc + 2][n]); u.w = f2bf(t[kc + 3][n]);
    *(ushort4*)(WT + (size_t)(n0 + n) * K + k0 + kc) = u;
  }
}

// ---------------- m97-style GEMM: C = A[MxK] * BT[NxK]^T, bf16 ----------------
__global__ __launch_bounds__(256) void gemm_bt(
    const ushort* __restrict__ A, const ushort* __restrict__ BT,
    void* __restrict__ Cv, void* __restrict__ C2v,
    int M, int N, int K, int mode)
{
  __shared__ __align__(16) ushort As[128 * 32];
  __shared__ __align__(16) ushort Bs[128 * 32];

  const int tid  = threadIdx.x;
  const int lane = tid & 63;
  const int w    = tid >> 6;
  const int wr = w >> 1, wc = w & 1;
  const int quad = lane >> 4, l16 = lane & 15;
  const int m0 = blockIdx.y * 128, n0 = blockIdx.x * 128;
  const int srow = lane >> 2;          // 0..15 row within 16-row chunk
  const int scol = (lane & 3) * 8;     // 0,8,16,24

  f32x4 acc[4][4];
#pragma unroll
  for (int bm = 0; bm < 4; ++bm)
#pragma unroll
    for (int bn = 0; bn < 4; ++bn)
      acc[bm][bn] = (f32x4){0.f, 0.f, 0.f, 0.f};

  for (int k0 = 0; k0 < K; k0 += 32) {
#pragma unroll
    for (int j = 0; j < 2; ++j) {
      const int rb = w * 32 + j * 16;  // wave-uniform
      async16(A  + (size_t)(m0 + rb + srow) * K + k0 + scol, &As[rb * 32]);
      async16(BT + (size_t)(n0 + rb + srow) * K + k0 + scol, &Bs[rb * 32]);
    }
    __syncthreads();   // drains vmcnt(0): staging complete

    bf16x8 af[4], bf[4];
#pragma unroll
    for (int bm = 0; bm < 4; ++bm)
      af[bm] = *(const bf16x8*)&As[(wr * 64 + bm * 16 + l16) * 32 + quad * 8];
#pragma unroll
    for (int bn = 0; bn < 4; ++bn)
      bf[bn] = *(const bf16x8*)&Bs[(wc * 64 + bn * 16 + l16) * 32 + quad * 8];
#pragma unroll
    for (int bm = 0; bm < 4; ++bm)
#pragma unroll
      for (int bn = 0; bn < 4; ++bn)
        acc[bm][bn] = __builtin_amdgcn_mfma_f32_16x16x32_bf16(
            af[bm], bf[bn], acc[bm][bn], 0, 0, 0);
    __syncthreads();
  }

  // C/D layout: row = quad*4 + i, col = l16 (m89-verified)
  if (mode == 0) {
    ushort* C = (ushort*)Cv;
#pragma unroll
    for (int bm = 0; bm < 4; ++bm) {
      int rbase = m0 + wr * 64 + bm * 16 + quad * 4;
#pragma unroll
      for (int bn = 0; bn < 4; ++bn) {
        int col = n0 + wc * 64 + bn * 16 + l16;
#pragma unroll
        for (int i = 0; i < 4; ++i)
          C[(size_t)(rbase + i) * N + col] = f2bf(acc[bm][bn][i]);
      }
    }
  } else if (mode == 1) {
    float* C = (float*)Cv;
#pragma unroll
    for (int bm = 0; bm < 4; ++bm) {
      int rbase = m0 + wr * 64 + bm * 16 + quad * 4;
#pragma unroll
      for (int bn = 0; bn < 4; ++bn) {
        int col = n0 + wc * 64 + bn * 16 + l16;
#pragma unroll
        for (int i = 0; i < 4; ++i)
          C[(size_t)(rbase + i) * N + col] = acc[bm][bn][i];
      }
    }
  } else {  // mode 2: KV fused
    if (n0 < 1024) {
      ushort* C = (ushort*)Cv;   // kb natural, stride KVDIM
#pragma unroll
      for (int bm = 0; bm < 4; ++bm) {
        int rbase = m0 + wr * 64 + bm * 16 + quad * 4;
#pragma unroll
        for (int bn = 0; bn < 4; ++bn) {
          int col = n0 + wc * 64 + bn * 16 + l16;
#pragma unroll
          for (int i = 0; i < 4; ++i)
            C[(size_t)(rbase + i) * KVDIM + col] = f2bf(acc[bm][bn][i]);
        }
      }
    } else {
      ushort* C2 = (ushort*)C2v; // V^T: C2[(col-1024)*SEQ + m], 4 m contiguous
#pragma unroll
      for (int bm = 0; bm < 4; ++bm) {
        int rbase = m0 + wr * 64 + bm * 16 + quad * 4;
#pragma unroll
        for (int bn = 0; bn < 4; ++bn) {
          int col = n0 + wc * 64 + bn * 16 + l16 - 1024;
          ushort4 u;
          u.x = f2bf(acc[bm][bn][0]); u.y = f2bf(acc[bm][bn][1]);
          u.z = f2bf(acc[bm][bn][2]); u.w = f2bf(acc[bm][bn][3]);
          *(ushort4*)(C2 + (size_t)col * SEQ + rbase) = u;
        }
      }
    }
  }
}

// ---------------- RoPE (interleaved pairs), in place on bf16 ------------------
__device__ __forceinline__ float bfhi(uint u) {
  union { uint i; float f; } v; v.i = u & 0xffff0000u; return v.f;
}
__device__ __forceinline__ float bflo(uint u) {
  union { uint i; float f; } v; v.i = u << 16; return v.f;
}
__global__ __launch_bounds__(256) void rope_kernel(
    ushort* __restrict__ t, const float* __restrict__ cosb,
    const float* __restrict__ sinb, int shift)
{
  int idx = blockIdx.x * 256 + threadIdx.x;
  int p  = idx & 63;
  int sh = idx >> 6;
  int s  = sh >> shift;
  uint* bp = (uint*)(t + ((size_t)sh << 7)) + p;
  uint u = *bp;
  float t1 = bflo(u), t2 = bfhi(u);
  float c  = cosb[(s << 6) + p];
  float sv = sinb[(s << 6) + p];
  float o1 = t1 * c - t2 * sv;
  float o2 = t1 * sv + t2 * c;
  *bp = ((uint)f2bf(o1)) | (((uint)f2bf(o2)) << 16);
}

// ---------------- MFMA flash attention v3: BQ=128, BK=64, 4 waves -------------
// Data-movement rework vs v2 (math identical):
//  * Q/K/VT staged via global_load_lds (no VGPR round trip, no ds_writes).
//  * Linear LDS rows + both-sides XOR chunk swizzle: slot = chunk ^ (row&7),
//    chunk = 16B. Pre-swizzled global src, swizzled ds_read. (rule 21)
//  * Single K buffer + double VT buffer; next tile's DMA issued after the
//    post-QK barrier so its latency hides under softmax+PV.
//  * Softmax 16-lane reductions via DPP (VALU), off the LDS pipe.
//  * s_setprio(1) around MFMA clusters (T5).
// LDS (ushort offs): K [0,8192) | VT0 [8192,16384) | VT1 [16384,24576) |
//                    P [24576,32768)  -> 64 KiB total, 2 blocks/CU.
#define OFF_VT0 8192
#define OFF_VT1 16384
#define OFF_P   24576

__global__ __launch_bounds__(256) void attn_mfma3(
    const ushort* __restrict__ Q, const ushort* __restrict__ K,
    const ushort* __restrict__ VT, ushort* __restrict__ O)
{
  __shared__ __align__(16) ushort SM[32768];   // 65536 B

  const int tid = threadIdx.x, lane = tid & 63, w = tid >> 6;
  const int l16 = lane & 15, quad = lane >> 4;
  const int h = blockIdx.y, kvh = h >> 2;
  const int q0 = blockIdx.x * 128;

  // ---- stage Q (128x128, swizzled) via DMA into [0,16384)
  {
    const int r4 = lane >> 4, c16 = lane & 15;
#pragma unroll
    for (int j = 0; j < 8; ++j) {
      int row = w * 32 + j * 4 + r4;
      async16(Q + (size_t)(q0 + row) * DIM + h * HD + ((c16 ^ (row & 7)) << 3),
              &SM[(w * 32 + j * 4) * 128]);
    }
  }
  __syncthreads();

  bf16x8 qf[2][4];
#pragma unroll
  for (int st = 0; st < 2; ++st) {
    const int row = w * 32 + st * 16 + l16;
#pragma unroll
    for (int ks = 0; ks < 4; ++ks)
      qf[st][ks] = *(const bf16x8*)&SM[row * 128 + (((ks * 4 + quad) ^ (row & 7)) << 3)];
  }
  __syncthreads();   // all qf reads complete before K(0)/VT(0) DMA lands

  // ---- prologue: stage K(0) and VT(0)
  {
    const int r4 = lane >> 4, c16 = lane & 15;
#pragma unroll
    for (int j = 0; j < 4; ++j) {
      int row = w * 16 + j * 4 + r4;
      async16(K + (size_t)row * KVDIM + kvh * HD + ((c16 ^ (row & 7)) << 3),
              &SM[(w * 16 + j * 4) * 128]);
    }
    const int r8 = lane >> 3, c8 = lane & 7;
#pragma unroll
    for (int j = 0; j < 4; ++j) {
      int row = w * 32 + j * 8 + r8;
      async16(VT + (size_t)(kvh * 128 + row) * SEQ + ((c8 ^ (row & 7)) << 3),
              &SM[OFF_VT0 + (w * 32 + j * 8) * 64]);
    }
  }

  f32x4 oacc[2][8];
#pragma unroll
  for (int st = 0; st < 2; ++st)
#pragma unroll
    for (int nt = 0; nt < 8; ++nt) oacc[st][nt] = (f32x4){0.f, 0.f, 0.f, 0.f};
  float m_i[2][4], l_i[2][4];
#pragma unroll
  for (int st = 0; st < 2; ++st)
#pragma unroll
    for (int r = 0; r < 4; ++r) { m_i[st][r] = -1e30f; l_i[st][r] = 0.f; }

  for (int t = 0; t < SEQ / 64; ++t) {
    __syncthreads();   // A: K(t)/VT(t) DMA drained (vmcnt0 at barrier)

    // ---- S = Q K^T : 32 MFMA (reads K buffer)
    f32x4 sacc[2][4];
#pragma unroll
    for (int st = 0; st < 2; ++st)
#pragma unroll
      for (int bn = 0; bn < 4; ++bn) sacc[st][bn] = (f32x4){0.f, 0.f, 0.f, 0.f};
    __builtin_amdgcn_s_setprio(1);
#pragma unroll
    for (int bn = 0; bn < 4; ++bn) {
      const int row = bn * 16 + l16;
#pragma unroll
      for (int ks = 0; ks < 4; ++ks) {
        bf16x8 kf = *(const bf16x8*)&SM[row * 128 + (((ks * 4 + quad) ^ (row & 7)) << 3)];
        sacc[0][bn] = __builtin_amdgcn_mfma_f32_16x16x32_bf16(qf[0][ks], kf, sacc[0][bn], 0, 0, 0);
        sacc[1][bn] = __builtin_amdgcn_mfma_f32_16x16x32_bf16(qf[1][ks], kf, sacc[1][bn], 0, 0, 0);
      }
    }
    __builtin_amdgcn_s_setprio(0);

    __syncthreads();   // B: all waves done reading K buffer

    // ---- prefetch next K / VT tile; DMA latency hides under softmax+PV
    if (t + 1 < SEQ / 64) {
      const int kb2 = (t + 1) * 64;
      const int r4 = lane >> 4, c16 = lane & 15;
#pragma unroll
      for (int j = 0; j < 4; ++j) {
        int row = w * 16 + j * 4 + r4;
        async16(K + (size_t)(kb2 + row) * KVDIM + kvh * HD + ((c16 ^ (row & 7)) << 3),
                &SM[(w * 16 + j * 4) * 128]);
      }
      const int r8 = lane >> 3, c8 = lane & 7;
      const int voff = (t & 1) ? OFF_VT0 : OFF_VT1;
#pragma unroll
      for (int j = 0; j < 4; ++j) {
        int row = w * 32 + j * 8 + r8;
        async16(VT + (size_t)(kvh * 128 + row) * SEQ + kb2 + ((c8 ^ (row & 7)) << 3),
                &SM[voff + (w * 32 + j * 8) * 64]);
      }
    }

    // ---- online softmax per strip/reg-row (DPP reductions) + P stores
    float alpha[2][4];
#pragma unroll
    for (int st = 0; st < 2; ++st)
#pragma unroll
      for (int r = 0; r < 4; ++r) {
        float s0 = sacc[st][0][r] * SCALE, s1 = sacc[st][1][r] * SCALE;
        float s2 = sacc[st][2][r] * SCALE, s3 = sacc[st][3][r] * SCALE;
        float lm = red16_max(fmaxf(fmaxf(s0, s1), fmaxf(s2, s3)));
        float mn = fmaxf(m_i[st][r], lm);
        float a = __expf(m_i[st][r] - mn);
        m_i[st][r] = mn; alpha[st][r] = a;
        float p0 = __expf(s0 - mn), p1 = __expf(s1 - mn);
        float p2 = __expf(s2 - mn), p3 = __expf(s3 - mn);
        float ls = red16_sum(p0 + p1 + p2 + p3);
        l_i[st][r] = l_i[st][r] * a + ls;
        const int prow = w * 32 + st * 16 + quad * 4 + r;   // wave-local P rows
        const int sw = prow & 7, ch0 = l16 >> 3, cl = l16 & 7;
        ushort* pb = &SM[OFF_P + prow * 64];
        pb[(((0 + ch0) ^ sw) << 3) + cl] = f2bf(p0);
        pb[(((2 + ch0) ^ sw) << 3) + cl] = f2bf(p1);
        pb[(((4 + ch0) ^ sw) << 3) + cl] = f2bf(p2);
        pb[(((6 + ch0) ^ sw) << 3) + cl] = f2bf(p3);
      }
#pragma unroll
    for (int st = 0; st < 2; ++st)
#pragma unroll
      for (int nt = 0; nt < 8; ++nt)
#pragma unroll
        for (int r = 0; r < 4; ++r) oacc[st][nt][r] *= alpha[st][r];

    // ---- PV : 32 MFMA (P wave-local; lgkm orders write->read within wave)
    const ushort* vtb = &SM[(t & 1) ? OFF_VT1 : OFF_VT0];
    __builtin_amdgcn_s_setprio(1);
#pragma unroll
    for (int kk = 0; kk < 2; ++kk) {
      const int pr0 = w * 32 + l16, pr1 = pr0 + 16;
      bf16x8 pf0 = *(const bf16x8*)&SM[OFF_P + pr0 * 64 + (((kk * 4 + quad) ^ (pr0 & 7)) << 3)];
      bf16x8 pf1 = *(const bf16x8*)&SM[OFF_P + pr1 * 64 + (((kk * 4 + quad) ^ (pr1 & 7)) << 3)];
#pragma unroll
      for (int nt = 0; nt < 8; ++nt) {
        const int vrow = nt * 16 + l16;
        bf16x8 vf = *(const bf16x8*)&vtb[vrow * 64 + (((kk * 4 + quad) ^ (vrow & 7)) << 3)];
        oacc[0][nt] = __builtin_amdgcn_mfma_f32_16x16x32_bf16(pf0, vf, oacc[0][nt], 0, 0, 0);
        oacc[1][nt] = __builtin_amdgcn_mfma_f32_16x16x32_bf16(pf1, vf, oacc[1][nt], 0, 0, 0);
      }
    }
    __builtin_amdgcn_s_setprio(0);
  }

  // ---- epilogue
#pragma unroll
  for (int st = 0; st < 2; ++st)
#pragma unroll
    for (int r = 0; r < 4; ++r) {
      float linv = 1.0f / l_i[st][r];
      int grow = q0 + w * 32 + st * 16 + quad * 4 + r;
#pragma unroll
      for (int nt = 0; nt < 8; ++nt)
        O[(size_t)grow * DIM + h * HD + nt * 16 + l16] = f2bf(oacc[st][nt][r] * linv);
    }
}

// ---------------- launcher ----------------------------------------------------
extern "C" void kernel_launch(void* const* d_in, const int* in_sizes, int n_in,
                              void* d_out, int out_size, void* d_ws, size_t ws_size,
                              hipStream_t stream) {
  const float* x  = (const float*)d_in[0];
  const float* fc = (const float*)d_in[1];
  const float* fs = (const float*)d_in[2];
  const float* wq = (const float*)d_in[3];
  const float* wk = (const float*)d_in[4];
  const float* wv = (const float*)d_in[5];
  const float* wo = (const float*)d_in[6];
  float* out = (float*)d_out;

  // ws (bf16 elems): xb | wT (wqT then woT) | wkvT | qb | kb | vT  = 92.4 MB
  ushort* xb   = (ushort*)d_ws;
  ushort* wT   = xb   + (size_t)SEQ * DIM;      // 4096x4096
  ushort* wkvT = wT   + (size_t)DIM * DIM;      // 2048x4096
  ushort* qb   = wkvT + (size_t)2048 * DIM;
  ushort* kb   = qb   + (size_t)SEQ * DIM;
  ushort* vT   = kb   + (size_t)SEQ * KVDIM;    // 1024 x 2048
  ushort* ab   = qb;                            // attention out aliases Q

  dim3 blk(256);

  convert_f32_bf16<<<(SEQ * DIM) / 2048, blk, 0, stream>>>(x, xb);
  transpose_w<<<dim3(DIM / 32, DIM / 32), blk, 0, stream>>>(wq, wT, DIM, DIM);
  transpose_w<<<dim3(KVDIM / 32, DIM / 32), blk, 0, stream>>>(wk, wkvT, DIM, KVDIM);
  transpose_w<<<dim3(KVDIM / 32, DIM / 32), blk, 0, stream>>>(wv, wkvT + (size_t)KVDIM * DIM, DIM, KVDIM);

  // Q projection
  gemm_bt<<<dim3(DIM / 128, SEQ / 128), blk, 0, stream>>>(xb, wT, qb, nullptr, SEQ, DIM, DIM, 0);
  // fused K/V projection (K natural -> kb, V transposed -> vT)
  gemm_bt<<<dim3(2048 / 128, SEQ / 128), blk, 0, stream>>>(xb, wkvT, kb, vT, SEQ, 2048, DIM, 2);

  rope_kernel<<<(SEQ * NH * 64) / 256, blk, 0, stream>>>(qb, fc, fs, 5);
  rope_kernel<<<(SEQ * NKV * 64) / 256, blk, 0, stream>>>(kb, fc, fs, 3);

  attn_mfma3<<<dim3(SEQ / 128, NH), blk, 0, stream>>>(qb, kb, vT, ab);

  // transpose wo into the (now dead) wqT region, then output projection
  transpose_w<<<dim3(DIM / 32, DIM / 32), blk, 0, stream>>>(wo, wT, DIM, DIM);
  gemm_bt<<<dim3(DIM / 128, SEQ / 128), blk, 0, stream>>>(ab, wT, out, nullptr, SEQ, DIM, DIM, 1);
}

// Round 3
// 603.143 us; speedup vs baseline: 1.1420x; 1.1420x over previous
//
#include <hip/hip_runtime.h>
#include <hip/hip_bf16.h>

#define SEQ   2048
#define DIM   4096
#define NH    32
#define NKV   8
#define HD    128
#define KVDIM 1024
#define SCALE 0.08838834764831845f

typedef __attribute__((ext_vector_type(8))) short bf16x8;
typedef __attribute__((ext_vector_type(4))) float f32x4;
typedef __attribute__((ext_vector_type(16))) float f32x16;

__device__ __forceinline__ ushort f2bf(float f) {  // RTN fp32 -> bf16 bits
  __hip_bfloat16 h = __float2bfloat16(f);
  return *reinterpret_cast<ushort*>(&h);
}

// async global->LDS, 16B per lane; LDS dest = wave-uniform base + lane*16
typedef const __attribute__((address_space(1))) uint* gas_ptr;
typedef __attribute__((address_space(3))) uint* las_ptr;
__device__ __forceinline__ void async16(const ushort* g, ushort* l) {
  __builtin_amdgcn_global_load_lds((gas_ptr)g, (las_ptr)l, 16, 0, 0);
}

// v_cvt_pk_bf16_f32: D[15:0]=bf16(lo), D[31:16]=bf16(hi)
__device__ __forceinline__ uint cvtpk(float lo, float hi) {
  uint r;
  asm("v_cvt_pk_bf16_f32 %0, %1, %2" : "=v"(r) : "v"(lo), "v"(hi));
  return r;
}
// v_permlane32_swap_b32 (dst.hi <-> src.lo): newA = {A.lo, B.lo}, newB = {A.hi, B.hi}
// NOTE: operands MUST be distinct live values (distinct VGPRs). Never call with
// provably-equal a,b — the allocator may coalesce them into one register.
__device__ __forceinline__ void plswap(uint& a, uint& b) {
  asm("v_permlane32_swap_b32 %0, %1" : "+v"(a), "+v"(b));
}

// ---------------- fp32 -> bf16 elementwise (x) --------------------------------
__global__ __launch_bounds__(256) void convert_f32_bf16(
    const float* __restrict__ in, ushort* __restrict__ out)
{
  int i = (blockIdx.x * 256 + threadIdx.x) * 8;
  float4 a = *(const float4*)(in + i);
  float4 b = *(const float4*)(in + i + 4);
  uint4 u;
  u.x = (uint)f2bf(a.x) | ((uint)f2bf(a.y) << 16);
  u.y = (uint)f2bf(a.z) | ((uint)f2bf(a.w) << 16);
  u.z = (uint)f2bf(b.x) | ((uint)f2bf(b.y) << 16);
  u.w = (uint)f2bf(b.z) | ((uint)f2bf(b.w) << 16);
  *(uint4*)(out + i) = u;
}

// ---------------- W[K][N] fp32 -> WT[N][K] bf16 (32x32 LDS tiles) -------------
__global__ __launch_bounds__(256) void transpose_w(
    const float* __restrict__ W, ushort* __restrict__ WT, int K, int N)
{
  __shared__ float t[32][33];
  const int k0 = blockIdx.y * 32, n0 = blockIdx.x * 32;
  const int tid = threadIdx.x;
  {
    int r = tid >> 3, c0 = (tid & 7) * 4;
    float4 v = *(const float4*)(W + (size_t)(k0 + r) * N + n0 + c0);
    t[r][c0] = v.x; t[r][c0 + 1] = v.y; t[r][c0 + 2] = v.z; t[r][c0 + 3] = v.w;
  }
  __syncthreads();
  {
    int n = tid >> 3, kc = (tid & 7) * 4;
    ushort4 u;
    u.x = f2bf(t[kc + 0][n]); u.y = f2bf(t[kc + 1][n]);
    u.z = f2bf(t[kc + 2][n]); u.w = f2bf(t[kc + 3][n]);
    *(ushort4*)(WT + (size_t)(n0 + n) * K + k0 + kc) = u;
  }
}

// ---------------- m97-style GEMM: C = A[MxK] * BT[NxK]^T, bf16 ----------------
__global__ __launch_bounds__(256) void gemm_bt(
    const ushort* __restrict__ A, const ushort* __restrict__ BT,
    void* __restrict__ Cv, void* __restrict__ C2v,
    int M, int N, int K, int mode)
{
  __shared__ __align__(16) ushort As[128 * 32];
  __shared__ __align__(16) ushort Bs[128 * 32];

  const int tid  = threadIdx.x;
  const int lane = tid & 63;
  const int w    = tid >> 6;
  const int wr = w >> 1, wc = w & 1;
  const int quad = lane >> 4, l16 = lane & 15;
  const int m0 = blockIdx.y * 128, n0 = blockIdx.x * 128;
  const int srow = lane >> 2;          // 0..15 row within 16-row chunk
  const int scol = (lane & 3) * 8;     // 0,8,16,24

  f32x4 acc[4][4];
#pragma unroll
  for (int bm = 0; bm < 4; ++bm)
#pragma unroll
    for (int bn = 0; bn < 4; ++bn)
      acc[bm][bn] = (f32x4){0.f, 0.f, 0.f, 0.f};

  for (int k0 = 0; k0 < K; k0 += 32) {
#pragma unroll
    for (int j = 0; j < 2; ++j) {
      const int rb = w * 32 + j * 16;  // wave-uniform
      async16(A  + (size_t)(m0 + rb + srow) * K + k0 + scol, &As[rb * 32]);
      async16(BT + (size_t)(n0 + rb + srow) * K + k0 + scol, &Bs[rb * 32]);
    }
    __syncthreads();   // drains vmcnt(0): staging complete

    bf16x8 af[4], bf[4];
#pragma unroll
    for (int bm = 0; bm < 4; ++bm)
      af[bm] = *(const bf16x8*)&As[(wr * 64 + bm * 16 + l16) * 32 + quad * 8];
#pragma unroll
    for (int bn = 0; bn < 4; ++bn)
      bf[bn] = *(const bf16x8*)&Bs[(wc * 64 + bn * 16 + l16) * 32 + quad * 8];
#pragma unroll
    for (int bm = 0; bm < 4; ++bm)
#pragma unroll
      for (int bn = 0; bn < 4; ++bn)
        acc[bm][bn] = __builtin_amdgcn_mfma_f32_16x16x32_bf16(
            af[bm], bf[bn], acc[bm][bn], 0, 0, 0);
    __syncthreads();
  }

  // C/D layout: row = quad*4 + i, col = l16 (m89-verified)
  if (mode == 0) {
    ushort* C = (ushort*)Cv;
#pragma unroll
    for (int bm = 0; bm < 4; ++bm) {
      int rbase = m0 + wr * 64 + bm * 16 + quad * 4;
#pragma unroll
      for (int bn = 0; bn < 4; ++bn) {
        int col = n0 + wc * 64 + bn * 16 + l16;
#pragma unroll
        for (int i = 0; i < 4; ++i)
          C[(size_t)(rbase + i) * N + col] = f2bf(acc[bm][bn][i]);
      }
    }
  } else if (mode == 1) {
    float* C = (float*)Cv;
#pragma unroll
    for (int bm = 0; bm < 4; ++bm) {
      int rbase = m0 + wr * 64 + bm * 16 + quad * 4;
#pragma unroll
      for (int bn = 0; bn < 4; ++bn) {
        int col = n0 + wc * 64 + bn * 16 + l16;
#pragma unroll
        for (int i = 0; i < 4; ++i)
          C[(size_t)(rbase + i) * N + col] = acc[bm][bn][i];
      }
    }
  } else {  // mode 2: KV fused
    if (n0 < 1024) {
      ushort* C = (ushort*)Cv;   // kb natural, stride KVDIM
#pragma unroll
      for (int bm = 0; bm < 4; ++bm) {
        int rbase = m0 + wr * 64 + bm * 16 + quad * 4;
#pragma unroll
        for (int bn = 0; bn < 4; ++bn) {
          int col = n0 + wc * 64 + bn * 16 + l16;
#pragma unroll
          for (int i = 0; i < 4; ++i)
            C[(size_t)(rbase + i) * KVDIM + col] = f2bf(acc[bm][bn][i]);
        }
      }
    } else {
      ushort* C2 = (ushort*)C2v; // V^T: C2[(col-1024)*SEQ + m], 4 m contiguous
#pragma unroll
      for (int bm = 0; bm < 4; ++bm) {
        int rbase = m0 + wr * 64 + bm * 16 + quad * 4;
#pragma unroll
        for (int bn = 0; bn < 4; ++bn) {
          int col = n0 + wc * 64 + bn * 16 + l16 - 1024;
          ushort4 u;
          u.x = f2bf(acc[bm][bn][0]); u.y = f2bf(acc[bm][bn][1]);
          u.z = f2bf(acc[bm][bn][2]); u.w = f2bf(acc[bm][bn][3]);
          *(ushort4*)(C2 + (size_t)col * SEQ + rbase) = u;
        }
      }
    }
  }
}

// ---------------- RoPE (interleaved pairs), in place on bf16 ------------------
__device__ __forceinline__ float bfhi(uint u) {
  union { uint i; float f; } v; v.i = u & 0xffff0000u; return v.f;
}
__device__ __forceinline__ float bflo(uint u) {
  union { uint i; float f; } v; v.i = u << 16; return v.f;
}
__global__ __launch_bounds__(256) void rope_kernel(
    ushort* __restrict__ t, const float* __restrict__ cosb,
    const float* __restrict__ sinb, int shift)
{
  int idx = blockIdx.x * 256 + threadIdx.x;
  int p  = idx & 63;
  int sh = idx >> 6;
  int s  = sh >> shift;
  uint* bp = (uint*)(t + ((size_t)sh << 7)) + p;
  uint u = *bp;
  float t1 = bflo(u), t2 = bfhi(u);
  float c  = cosb[(s << 6) + p];
  float sv = sinb[(s << 6) + p];
  float o1 = t1 * c - t2 * sv;
  float o2 = t1 * sv + t2 * c;
  *bp = ((uint)f2bf(o1)) | (((uint)f2bf(o2)) << 16);
}

// ---------------- MFMA flash attention v5: 32x32 swapped-QK, in-reg softmax ---
// = v4 with the two softmax cross-half reductions done via __shfl_xor(.,32)
// instead of same-value plswap (register-coalescing hazard: plswap with two
// names of ONE value can land both asm operands in the same VGPR).
// Per wave: 32 q-rows. S^T = mfma(K,Q): lane owns q = lane&31 entirely.
// P in registers (cvt_pk + permlane32_swap with DISTINCT values, T12).
// PV: O^T = V^T * P^T. Defer-max THR=8 (T13). DMA staging, XOR chunk swizzle
// both-sides. K single-buffer, V^T double-buffer, prefetch after barrier B.
#define OFF_V0U 8192
#define OFF_V1U 16384
#define NT (SEQ / 64)

__device__ __forceinline__ void stage_K(const ushort* __restrict__ K, ushort* SM,
                                        int w, int lane, int kb, int kvh) {
  const int r4 = lane >> 4, c16 = lane & 15;
#pragma unroll
  for (int j = 0; j < 4; ++j) {
    int rb = w * 16 + j * 4, row = rb + r4;
    int c = c16 ^ (row & 15);
    async16(K + (size_t)(kb + row) * KVDIM + kvh * HD + c * 8, &SM[rb * 128]);
  }
}
__device__ __forceinline__ void stage_V(const ushort* __restrict__ VT, ushort* SMv,
                                        int w, int lane, int kb, int kvh) {
  const int r8 = lane >> 3, c8 = lane & 7;
#pragma unroll
  for (int j = 0; j < 4; ++j) {
    int rb = w * 32 + j * 8, row = rb + r8;
    int c = c8 ^ (row & 7);
    async16(VT + (size_t)(kvh * 128 + row) * SEQ + kb + c * 8, &SMv[rb * 64]);
  }
}

__global__ __launch_bounds__(256, 2) void attn_mfma5(
    const ushort* __restrict__ Q, const ushort* __restrict__ K,
    const ushort* __restrict__ VT, ushort* __restrict__ O)
{
  __shared__ __align__(16) ushort SM[24576];   // 49152 B

  const int tid = threadIdx.x, lane = tid & 63, w = tid >> 6;
  const int l31 = lane & 31, hi = lane >> 5;
  const int kx = l31 & 15;          // row&15 for K/Q reads (rows ≡ l31 mod 32)
  const int vx = lane & 7;          // row&7 for V reads
  const int h = blockIdx.y, kvh = h >> 2;
  const int q0 = blockIdx.x * 128;

  // ---- stage Q (128 rows x 256B, swizzled chunks) via DMA into [0,16384)
  {
    const int r4 = lane >> 4, c16 = lane & 15;
#pragma unroll
    for (int j = 0; j < 8; ++j) {
      int rb = w * 32 + j * 4, row = rb + r4;
      int c = c16 ^ (row & 15);
      async16(Q + (size_t)(q0 + row) * DIM + h * HD + c * 8, &SM[rb * 128]);
    }
  }
  __syncthreads();

  // ---- Q fragments in registers: B-operand, col(q) = l31
  bf16x8 qf[8];
#pragma unroll
  for (int ks = 0; ks < 8; ++ks) {
    int cc = ((2 * ks + hi) ^ kx) << 3;
    qf[ks] = *(const bf16x8*)&SM[(w * 32 + l31) * 128 + cc];
  }
  __syncthreads();   // all Q reads done before K/V DMA lands

  // ---- prologue: stage K(0), VT(0)
  stage_K(K, SM, w, lane, 0, kvh);
  stage_V(VT, &SM[OFF_V0U], w, lane, 0, kvh);

  f32x16 oacc[4];
#pragma unroll
  for (int dt = 0; dt < 4; ++dt)
#pragma unroll
    for (int r = 0; r < 16; ++r) oacc[dt][r] = 0.f;
  float m_i = -1e30f, l_i = 0.f;

  for (int t = 0; t < NT; ++t) {
    __syncthreads();   // A: K(t)/VT(t) staging drained (vmcnt0 at barrier)

    // ---- S^T = K Q^T : 16 MFMA 32x32x16 (A = K rows, B = Q rows)
    f32x16 s0, s1;
#pragma unroll
    for (int r = 0; r < 16; ++r) { s0[r] = 0.f; s1[r] = 0.f; }
    __builtin_amdgcn_s_setprio(1);
#pragma unroll
    for (int ks = 0; ks < 8; ++ks) {
      int cc = ((2 * ks + hi) ^ kx) << 3;
      bf16x8 k0 = *(const bf16x8*)&SM[l31 * 128 + cc];
      bf16x8 k1 = *(const bf16x8*)&SM[(32 + l31) * 128 + cc];
      s0 = __builtin_amdgcn_mfma_f32_32x32x16_bf16(k0, qf[ks], s0, 0, 0, 0);
      s1 = __builtin_amdgcn_mfma_f32_32x32x16_bf16(k1, qf[ks], s1, 0, 0, 0);
    }
    __builtin_amdgcn_s_setprio(0);

    __syncthreads();   // B: all waves done reading K buffer

    // ---- prefetch next K / VT (latency hides under softmax + PV)
    if (t + 1 < NT) {
      stage_K(K, SM, w, lane, (t + 1) * 64, kvh);
      stage_V(VT, &SM[((t + 1) & 1) ? OFF_V1U : OFF_V0U], w, lane, (t + 1) * 64, kvh);
    }

    // ---- in-register online softmax (lane owns q = l31; kv split across hi)
    float tm[16];
#pragma unroll
    for (int i = 0; i < 16; ++i) tm[i] = fmaxf(s0[i], s1[i]);
#pragma unroll
    for (int d = 8; d >= 1; d >>= 1)
#pragma unroll
      for (int i = 0; i < 8; ++i) if (i < d) tm[i] = fmaxf(tm[i], tm[i + d]);
    float lm = fmaxf(tm[0], __shfl_xor(tm[0], 32));   // cross-half exchange
    float lmS = lm * SCALE;
    float mn;
    if (__any(lmS > m_i + 8.0f)) {        // rescale path (defer-max, THR=8)
      mn = fmaxf(m_i, lmS);
      float al = __expf(m_i - mn);
      m_i = mn; l_i *= al;
#pragma unroll
      for (int dt = 0; dt < 4; ++dt)
#pragma unroll
        for (int r = 0; r < 16; ++r) oacc[dt][r] *= al;
    } else mn = m_i;

    float p0[16], p1[16];
#pragma unroll
    for (int r = 0; r < 16; ++r) p0[r] = __expf(fmaf(s0[r], SCALE, -mn));
#pragma unroll
    for (int r = 0; r < 16; ++r) p1[r] = __expf(fmaf(s1[r], SCALE, -mn));
    {
      float ts[16];
#pragma unroll
      for (int i = 0; i < 16; ++i) ts[i] = p0[i] + p1[i];
#pragma unroll
      for (int d = 8; d >= 1; d >>= 1)
#pragma unroll
        for (int i = 0; i < 8; ++i) if (i < d) ts[i] += ts[i + d];
      l_i += ts[0] + __shfl_xor(ts[0], 32);           // cross-half exchange
    }

    // ---- P -> bf16 PV B-operand frags (T12): 16 cvt_pk + 8 permlane32_swap
    // pf[ks][j] = P[q=l31][kv = ks*16 + hi*8 + j]; all plswap operands are
    // distinct live values (safe).
    bf16x8 pf[4];
    {
      uint a0 = cvtpk(p0[0], p0[1]),  b0 = cvtpk(p0[4], p0[5]);   plswap(a0, b0);
      uint a1 = cvtpk(p0[2], p0[3]),  b1 = cvtpk(p0[6], p0[7]);   plswap(a1, b1);
      uint4 u0 = {a0, a1, b0, b1};  pf[0] = *(bf16x8*)&u0;
      uint a2 = cvtpk(p0[8], p0[9]),  b2 = cvtpk(p0[12], p0[13]); plswap(a2, b2);
      uint a3 = cvtpk(p0[10], p0[11]),b3 = cvtpk(p0[14], p0[15]); plswap(a3, b3);
      uint4 u1 = {a2, a3, b2, b3};  pf[1] = *(bf16x8*)&u1;
      uint a4 = cvtpk(p1[0], p1[1]),  b4 = cvtpk(p1[4], p1[5]);   plswap(a4, b4);
      uint a5 = cvtpk(p1[2], p1[3]),  b5 = cvtpk(p1[6], p1[7]);   plswap(a5, b5);
      uint4 u2 = {a4, a5, b4, b5};  pf[2] = *(bf16x8*)&u2;
      uint a6 = cvtpk(p1[8], p1[9]),  b6 = cvtpk(p1[12], p1[13]); plswap(a6, b6);
      uint a7 = cvtpk(p1[10], p1[11]),b7 = cvtpk(p1[14], p1[15]); plswap(a7, b7);
      uint4 u3 = {a6, a7, b6, b7};  pf[3] = *(bf16x8*)&u3;
    }

    // ---- PV: O^T += V^T P^T : 16 MFMA (A = V^T rows=d, B = P rows=q)
    const int vbU = (t & 1) ? OFF_V1U : OFF_V0U;
    __builtin_amdgcn_s_setprio(1);
#pragma unroll
    for (int ks = 0; ks < 4; ++ks) {
      int cc = ((2 * ks + hi) ^ vx) << 3;
#pragma unroll
      for (int dt = 0; dt < 4; ++dt) {
        bf16x8 vf = *(const bf16x8*)&SM[vbU + (dt * 32 + l31) * 64 + cc];
        oacc[dt] = __builtin_amdgcn_mfma_f32_32x32x16_bf16(vf, pf[ks], oacc[dt], 0, 0, 0);
      }
    }
    __builtin_amdgcn_s_setprio(0);
  }

  // ---- epilogue: O^T -> per-wave LDS transpose -> coalesced global store
  float linv = 1.0f / l_i;
  const int RB = w * 4096;
#pragma unroll
  for (int dt = 0; dt < 4; ++dt)
#pragma unroll
    for (int r = 0; r < 16; ++r) {
      int d = dt * 32 + (r & 3) + 8 * (r >> 2) + 4 * hi;
      SM[RB + l31 * 128 + (((d >> 3) ^ (l31 & 15)) << 3) + (d & 7)] =
          f2bf(oacc[dt][r] * linv);
    }
  {
    const int r4 = lane >> 4, c16 = lane & 15;
#pragma unroll
    for (int i = 0; i < 8; ++i) {
      int qq = i * 4 + r4;
      uint4 v = *(const uint4*)&SM[RB + qq * 128 + ((c16 ^ (qq & 15)) << 3)];
      *(uint4*)(O + (size_t)(q0 + w * 32 + qq) * DIM + h * HD + c16 * 8) = v;
    }
  }
}

// ---------------- launcher ----------------------------------------------------
extern "C" void kernel_launch(void* const* d_in, const int* in_sizes, int n_in,
                              void* d_out, int out_size, void* d_ws, size_t ws_size,
                              hipStream_t stream) {
  const float* x  = (const float*)d_in[0];
  const float* fc = (const float*)d_in[1];
  const float* fs = (const float*)d_in[2];
  const float* wq = (const float*)d_in[3];
  const float* wk = (const float*)d_in[4];
  const float* wv = (const float*)d_in[5];
  const float* wo = (const float*)d_in[6];
  float* out = (float*)d_out;

  // ws (bf16 elems): xb | wT (wqT then woT) | wkvT | qb | kb | vT  = 92.4 MB
  ushort* xb   = (ushort*)d_ws;
  ushort* wT   = xb   + (size_t)SEQ * DIM;      // 4096x4096
  ushort* wkvT = wT   + (size_t)DIM * DIM;      // 2048x4096
  ushort* qb   = wkvT + (size_t)2048 * DIM;
  ushort* kb   = qb   + (size_t)SEQ * DIM;
  ushort* vT   = kb   + (size_t)SEQ * KVDIM;    // 1024 x 2048
  ushort* ab   = qb;                            // attention out aliases Q

  dim3 blk(256);

  convert_f32_bf16<<<(SEQ * DIM) / 2048, blk, 0, stream>>>(x, xb);
  transpose_w<<<dim3(DIM / 32, DIM / 32), blk, 0, stream>>>(wq, wT, DIM, DIM);
  transpose_w<<<dim3(KVDIM / 32, DIM / 32), blk, 0, stream>>>(wk, wkvT, DIM, KVDIM);
  transpose_w<<<dim3(KVDIM / 32, DIM / 32), blk, 0, stream>>>(wv, wkvT + (size_t)KVDIM * DIM, DIM, KVDIM);

  // Q projection
  gemm_bt<<<dim3(DIM / 128, SEQ / 128), blk, 0, stream>>>(xb, wT, qb, nullptr, SEQ, DIM, DIM, 0);
  // fused K/V projection (K natural -> kb, V transposed -> vT)
  gemm_bt<<<dim3(2048 / 128, SEQ / 128), blk, 0, stream>>>(xb, wkvT, kb, vT, SEQ, 2048, DIM, 2);

  rope_kernel<<<(SEQ * NH * 64) / 256, blk, 0, stream>>>(qb, fc, fs, 5);
  rope_kernel<<<(SEQ * NKV * 64) / 256, blk, 0, stream>>>(kb, fc, fs, 3);

  attn_mfma5<<<dim3(SEQ / 128, NH), blk, 0, stream>>>(qb, kb, vT, ab);

  // transpose wo into the (now dead) wqT region, then output projection
  transpose_w<<<dim3(DIM / 32, DIM / 32), blk, 0, stream>>>(wo, wT, DIM, DIM);
  gemm_bt<<<dim3(DIM / 128, SEQ / 128), blk, 0, stream>>>(ab, wT, out, nullptr, SEQ, DIM, DIM, 1);
}

// Round 4
// 540.482 us; speedup vs baseline: 1.2744x; 1.1159x over previous
//
#include <hip/hip_runtime.h>
#include <hip/hip_bf16.h>

#define SEQ   2048
#define DIM   4096
#define NH    32
#define NKV   8
#define HD    128
#define KVDIM 1024
#define SCALE 0.08838834764831845f

typedef __attribute__((ext_vector_type(8))) short bf16x8;
typedef __attribute__((ext_vector_type(4))) float f32x4;
typedef __attribute__((ext_vector_type(16))) float f32x16;

__device__ __forceinline__ ushort f2bf(float f) {  // RTN fp32 -> bf16 bits
  __hip_bfloat16 h = __float2bfloat16(f);
  return *reinterpret_cast<ushort*>(&h);
}

// async global->LDS, 16B per lane; LDS dest = wave-uniform base + lane*16
typedef const __attribute__((address_space(1))) uint* gas_ptr;
typedef __attribute__((address_space(3))) uint* las_ptr;
__device__ __forceinline__ void async16(const ushort* g, ushort* l) {
  __builtin_amdgcn_global_load_lds((gas_ptr)g, (las_ptr)l, 16, 0, 0);
}

// v_cvt_pk_bf16_f32: D[15:0]=bf16(lo), D[31:16]=bf16(hi)
__device__ __forceinline__ uint cvtpk(float lo, float hi) {
  uint r;
  asm("v_cvt_pk_bf16_f32 %0, %1, %2" : "=v"(r) : "v"(lo), "v"(hi));
  return r;
}
// v_permlane32_swap_b32 (dst.hi <-> src.lo): newA = {A.lo, B.lo}, newB = {A.hi, B.hi}
// NOTE: operands MUST be distinct live values (distinct VGPRs). Never call with
// provably-equal a,b — the allocator may coalesce them into one register.
__device__ __forceinline__ void plswap(uint& a, uint& b) {
  asm("v_permlane32_swap_b32 %0, %1" : "+v"(a), "+v"(b));
}

// ---------------- fp32 -> bf16 elementwise (x) --------------------------------
__global__ __launch_bounds__(256) void convert_f32_bf16(
    const float* __restrict__ in, ushort* __restrict__ out)
{
  int i = (blockIdx.x * 256 + threadIdx.x) * 8;
  float4 a = *(const float4*)(in + i);
  float4 b = *(const float4*)(in + i + 4);
  uint4 u;
  u.x = (uint)f2bf(a.x) | ((uint)f2bf(a.y) << 16);
  u.y = (uint)f2bf(a.z) | ((uint)f2bf(a.w) << 16);
  u.z = (uint)f2bf(b.x) | ((uint)f2bf(b.y) << 16);
  u.w = (uint)f2bf(b.z) | ((uint)f2bf(b.w) << 16);
  *(uint4*)(out + i) = u;
}

// ---------------- W[K][N] fp32 -> WT[N][K] bf16 (32x32 LDS tiles) -------------
__global__ __launch_bounds__(256) void transpose_w(
    const float* __restrict__ W, ushort* __restrict__ WT, int K, int N)
{
  __shared__ float t[32][33];
  const int k0 = blockIdx.y * 32, n0 = blockIdx.x * 32;
  const int tid = threadIdx.x;
  {
    int r = tid >> 3, c0 = (tid & 7) * 4;
    float4 v = *(const float4*)(W + (size_t)(k0 + r) * N + n0 + c0);
    t[r][c0] = v.x; t[r][c0 + 1] = v.y; t[r][c0 + 2] = v.z; t[r][c0 + 3] = v.w;
  }
  __syncthreads();
  {
    int n = tid >> 3, kc = (tid & 7) * 4;
    ushort4 u;
    u.x = f2bf(t[kc + 0][n]); u.y = f2bf(t[kc + 1][n]);
    u.z = f2bf(t[kc + 2][n]); u.w = f2bf(t[kc + 3][n]);
    *(ushort4*)(WT + (size_t)(n0 + n) * K + k0 + kc) = u;
  }
}

// ---------------- GEMM v2: C = A[MxK] * BT[NxK]^T, bf16, BK=64 ----------------
// 128x128 tile, BK=64 (32 MFMA/wave per barrier pair — halves vmcnt(0) drains
// vs BK=32), 4 waves 2x2. XOR chunk swizzle both-sides (rows are 128 B; linear
// would be 16-way bank conflict on ds_read_b128):
//   stage:  lane l -> LDS row rb+(l>>3), slot (l&7); source chunk (l&7)^(l>>3)
//   read:   global chunk g lives at slot g ^ (row&7)   [row&7 == l16&7]
// mode 0: bf16 C stride N. mode 1: fp32 C stride N.
// mode 2: fused QKV epilogue: col<4096 -> qb (stride DIM);
//         col<5120 -> kb (stride KVDIM); else -> vT[(col-5120)*SEQ + m]
//         (Cv = qb, C2v = kb, vT = kb + SEQ*KVDIM).
__global__ __launch_bounds__(256) void gemm_bt(
    const ushort* __restrict__ A, const ushort* __restrict__ BT,
    void* __restrict__ Cv, void* __restrict__ C2v,
    int M, int N, int K, int mode)
{
  __shared__ __align__(16) ushort As[128 * 64];
  __shared__ __align__(16) ushort Bs[128 * 64];

  const int tid  = threadIdx.x;
  const int lane = tid & 63;
  const int w    = tid >> 6;
  const int wr = w >> 1, wc = w & 1;
  const int quad = lane >> 4, l16 = lane & 15;
  const int m0 = blockIdx.y * 128, n0 = blockIdx.x * 128;
  const int srow8 = lane >> 3;              // 0..7 row within 8-row chunk
  const int sswz  = ((lane & 7) ^ srow8) << 3;  // pre-swizzled source chunk

  f32x4 acc[4][4];
#pragma unroll
  for (int bm = 0; bm < 4; ++bm)
#pragma unroll
    for (int bn = 0; bn < 4; ++bn)
      acc[bm][bn] = (f32x4){0.f, 0.f, 0.f, 0.f};

  for (int k0 = 0; k0 < K; k0 += 64) {
#pragma unroll
    for (int j = 0; j < 4; ++j) {
      const int rb = w * 32 + j * 8;   // wave-uniform
      async16(A  + (size_t)(m0 + rb + srow8) * K + k0 + sswz, &As[rb * 64]);
      async16(BT + (size_t)(n0 + rb + srow8) * K + k0 + sswz, &Bs[rb * 64]);
    }
    __syncthreads();   // drains vmcnt(0): staging complete

#pragma unroll
    for (int s = 0; s < 2; ++s) {
      bf16x8 af[4], bf[4];
#pragma unroll
      for (int bm = 0; bm < 4; ++bm) {
        const int row = wr * 64 + bm * 16 + l16;
        af[bm] = *(const bf16x8*)&As[row * 64 + (((s * 4 + quad) ^ (row & 7)) << 3)];
      }
#pragma unroll
      for (int bn = 0; bn < 4; ++bn) {
        const int row = wc * 64 + bn * 16 + l16;
        bf[bn] = *(const bf16x8*)&Bs[row * 64 + (((s * 4 + quad) ^ (row & 7)) << 3)];
      }
#pragma unroll
      for (int bm = 0; bm < 4; ++bm)
#pragma unroll
        for (int bn = 0; bn < 4; ++bn)
          acc[bm][bn] = __builtin_amdgcn_mfma_f32_16x16x32_bf16(
              af[bm], bf[bn], acc[bm][bn], 0, 0, 0);
    }
    __syncthreads();
  }

  // C/D layout: row = quad*4 + i, col = l16 (m89-verified)
  if (mode == 0) {
    ushort* C = (ushort*)Cv;
#pragma unroll
    for (int bm = 0; bm < 4; ++bm) {
      int rbase = m0 + wr * 64 + bm * 16 + quad * 4;
#pragma unroll
      for (int bn = 0; bn < 4; ++bn) {
        int col = n0 + wc * 64 + bn * 16 + l16;
#pragma unroll
        for (int i = 0; i < 4; ++i)
          C[(size_t)(rbase + i) * N + col] = f2bf(acc[bm][bn][i]);
      }
    }
  } else if (mode == 1) {
    float* C = (float*)Cv;
#pragma unroll
    for (int bm = 0; bm < 4; ++bm) {
      int rbase = m0 + wr * 64 + bm * 16 + quad * 4;
#pragma unroll
      for (int bn = 0; bn < 4; ++bn) {
        int col = n0 + wc * 64 + bn * 16 + l16;
#pragma unroll
        for (int i = 0; i < 4; ++i)
          C[(size_t)(rbase + i) * N + col] = acc[bm][bn][i];
      }
    }
  } else {  // mode 2: fused QKV
    if (n0 < 4096) {
      ushort* C = (ushort*)Cv;   // qb natural, stride DIM
#pragma unroll
      for (int bm = 0; bm < 4; ++bm) {
        int rbase = m0 + wr * 64 + bm * 16 + quad * 4;
#pragma unroll
        for (int bn = 0; bn < 4; ++bn) {
          int col = n0 + wc * 64 + bn * 16 + l16;
#pragma unroll
          for (int i = 0; i < 4; ++i)
            C[(size_t)(rbase + i) * DIM + col] = f2bf(acc[bm][bn][i]);
        }
      }
    } else if (n0 < 5120) {
      ushort* C = (ushort*)C2v;  // kb natural, stride KVDIM
#pragma unroll
      for (int bm = 0; bm < 4; ++bm) {
        int rbase = m0 + wr * 64 + bm * 16 + quad * 4;
#pragma unroll
        for (int bn = 0; bn < 4; ++bn) {
          int col = n0 + wc * 64 + bn * 16 + l16 - 4096;
#pragma unroll
          for (int i = 0; i < 4; ++i)
            C[(size_t)(rbase + i) * KVDIM + col] = f2bf(acc[bm][bn][i]);
        }
      }
    } else {
      ushort* C2 = (ushort*)C2v + (size_t)SEQ * KVDIM; // vT[(col-5120)*SEQ + m]
#pragma unroll
      for (int bm = 0; bm < 4; ++bm) {
        int rbase = m0 + wr * 64 + bm * 16 + quad * 4;
#pragma unroll
        for (int bn = 0; bn < 4; ++bn) {
          int col = n0 + wc * 64 + bn * 16 + l16 - 5120;
          ushort4 u;
          u.x = f2bf(acc[bm][bn][0]); u.y = f2bf(acc[bm][bn][1]);
          u.z = f2bf(acc[bm][bn][2]); u.w = f2bf(acc[bm][bn][3]);
          *(ushort4*)(C2 + (size_t)col * SEQ + rbase) = u;
        }
      }
    }
  }
}

// ---------------- RoPE (interleaved pairs), in place on bf16 ------------------
__device__ __forceinline__ float bfhi(uint u) {
  union { uint i; float f; } v; v.i = u & 0xffff0000u; return v.f;
}
__device__ __forceinline__ float bflo(uint u) {
  union { uint i; float f; } v; v.i = u << 16; return v.f;
}
__global__ __launch_bounds__(256) void rope_kernel(
    ushort* __restrict__ t, const float* __restrict__ cosb,
    const float* __restrict__ sinb, int shift)
{
  int idx = blockIdx.x * 256 + threadIdx.x;
  int p  = idx & 63;
  int sh = idx >> 6;
  int s  = sh >> shift;
  uint* bp = (uint*)(t + ((size_t)sh << 7)) + p;
  uint u = *bp;
  float t1 = bflo(u), t2 = bfhi(u);
  float c  = cosb[(s << 6) + p];
  float sv = sinb[(s << 6) + p];
  float o1 = t1 * c - t2 * sv;
  float o2 = t1 * sv + t2 * c;
  *bp = ((uint)f2bf(o1)) | (((uint)f2bf(o2)) << 16);
}

// ---------------- MFMA flash attention v5: 32x32 swapped-QK, in-reg softmax ---
// Per wave: 32 q-rows. S^T = mfma(K,Q): lane owns q = lane&31 entirely.
// P in registers (cvt_pk + permlane32_swap with DISTINCT values, T12).
// PV: O^T = V^T * P^T. Defer-max THR=8 (T13). DMA staging, XOR chunk swizzle
// both-sides. K single-buffer, V^T double-buffer, prefetch after barrier B.
#define OFF_V0U 8192
#define OFF_V1U 16384
#define NT (SEQ / 64)

__device__ __forceinline__ void stage_K(const ushort* __restrict__ K, ushort* SM,
                                        int w, int lane, int kb, int kvh) {
  const int r4 = lane >> 4, c16 = lane & 15;
#pragma unroll
  for (int j = 0; j < 4; ++j) {
    int rb = w * 16 + j * 4, row = rb + r4;
    int c = c16 ^ (row & 15);
    async16(K + (size_t)(kb + row) * KVDIM + kvh * HD + c * 8, &SM[rb * 128]);
  }
}
__device__ __forceinline__ void stage_V(const ushort* __restrict__ VT, ushort* SMv,
                                        int w, int lane, int kb, int kvh) {
  const int r8 = lane >> 3, c8 = lane & 7;
#pragma unroll
  for (int j = 0; j < 4; ++j) {
    int rb = w * 32 + j * 8, row = rb + r8;
    int c = c8 ^ (row & 7);
    async16(VT + (size_t)(kvh * 128 + row) * SEQ + kb + c * 8, &SMv[rb * 64]);
  }
}

__global__ __launch_bounds__(256, 2) void attn_mfma5(
    const ushort* __restrict__ Q, const ushort* __restrict__ K,
    const ushort* __restrict__ VT, ushort* __restrict__ O)
{
  __shared__ __align__(16) ushort SM[24576];   // 49152 B

  const int tid = threadIdx.x, lane = tid & 63, w = tid >> 6;
  const int l31 = lane & 31, hi = lane >> 5;
  const int kx = l31 & 15;          // row&15 for K/Q reads (rows ≡ l31 mod 32)
  const int vx = lane & 7;          // row&7 for V reads
  const int h = blockIdx.y, kvh = h >> 2;
  const int q0 = blockIdx.x * 128;

  // ---- stage Q (128 rows x 256B, swizzled chunks) via DMA into [0,16384)
  {
    const int r4 = lane >> 4, c16 = lane & 15;
#pragma unroll
    for (int j = 0; j < 8; ++j) {
      int rb = w * 32 + j * 4, row = rb + r4;
      int c = c16 ^ (row & 15);
      async16(Q + (size_t)(q0 + row) * DIM + h * HD + c * 8, &SM[rb * 128]);
    }
  }
  __syncthreads();

  // ---- Q fragments in registers: B-operand, col(q) = l31
  bf16x8 qf[8];
#pragma unroll
  for (int ks = 0; ks < 8; ++ks) {
    int cc = ((2 * ks + hi) ^ kx) << 3;
    qf[ks] = *(const bf16x8*)&SM[(w * 32 + l31) * 128 + cc];
  }
  __syncthreads();   // all Q reads done before K/V DMA lands

  // ---- prologue: stage K(0), VT(0)
  stage_K(K, SM, w, lane, 0, kvh);
  stage_V(VT, &SM[OFF_V0U], w, lane, 0, kvh);

  f32x16 oacc[4];
#pragma unroll
  for (int dt = 0; dt < 4; ++dt)
#pragma unroll
    for (int r = 0; r < 16; ++r) oacc[dt][r] = 0.f;
  float m_i = -1e30f, l_i = 0.f;

  for (int t = 0; t < NT; ++t) {
    __syncthreads();   // A: K(t)/VT(t) staging drained (vmcnt0 at barrier)

    // ---- S^T = K Q^T : 16 MFMA 32x32x16 (A = K rows, B = Q rows)
    f32x16 s0, s1;
#pragma unroll
    for (int r = 0; r < 16; ++r) { s0[r] = 0.f; s1[r] = 0.f; }
    __builtin_amdgcn_s_setprio(1);
#pragma unroll
    for (int ks = 0; ks < 8; ++ks) {
      int cc = ((2 * ks + hi) ^ kx) << 3;
      bf16x8 k0 = *(const bf16x8*)&SM[l31 * 128 + cc];
      bf16x8 k1 = *(const bf16x8*)&SM[(32 + l31) * 128 + cc];
      s0 = __builtin_amdgcn_mfma_f32_32x32x16_bf16(k0, qf[ks], s0, 0, 0, 0);
      s1 = __builtin_amdgcn_mfma_f32_32x32x16_bf16(k1, qf[ks], s1, 0, 0, 0);
    }
    __builtin_amdgcn_s_setprio(0);

    __syncthreads();   // B: all waves done reading K buffer

    // ---- prefetch next K / VT (latency hides under softmax + PV)
    if (t + 1 < NT) {
      stage_K(K, SM, w, lane, (t + 1) * 64, kvh);
      stage_V(VT, &SM[((t + 1) & 1) ? OFF_V1U : OFF_V0U], w, lane, (t + 1) * 64, kvh);
    }

    // ---- in-register online softmax (lane owns q = l31; kv split across hi)
    float tm[16];
#pragma unroll
    for (int i = 0; i < 16; ++i) tm[i] = fmaxf(s0[i], s1[i]);
#pragma unroll
    for (int d = 8; d >= 1; d >>= 1)
#pragma unroll
      for (int i = 0; i < 8; ++i) if (i < d) tm[i] = fmaxf(tm[i], tm[i + d]);
    float lm = fmaxf(tm[0], __shfl_xor(tm[0], 32));   // cross-half exchange
    float lmS = lm * SCALE;
    float mn;
    if (__any(lmS > m_i + 8.0f)) {        // rescale path (defer-max, THR=8)
      mn = fmaxf(m_i, lmS);
      float al = __expf(m_i - mn);
      m_i = mn; l_i *= al;
#pragma unroll
      for (int dt = 0; dt < 4; ++dt)
#pragma unroll
        for (int r = 0; r < 16; ++r) oacc[dt][r] *= al;
    } else mn = m_i;

    float p0[16], p1[16];
#pragma unroll
    for (int r = 0; r < 16; ++r) p0[r] = __expf(fmaf(s0[r], SCALE, -mn));
#pragma unroll
    for (int r = 0; r < 16; ++r) p1[r] = __expf(fmaf(s1[r], SCALE, -mn));
    {
      float ts[16];
#pragma unroll
      for (int i = 0; i < 16; ++i) ts[i] = p0[i] + p1[i];
#pragma unroll
      for (int d = 8; d >= 1; d >>= 1)
#pragma unroll
        for (int i = 0; i < 8; ++i) if (i < d) ts[i] += ts[i + d];
      l_i += ts[0] + __shfl_xor(ts[0], 32);           // cross-half exchange
    }

    // ---- P -> bf16 PV B-operand frags (T12): 16 cvt_pk + 8 permlane32_swap
    // pf[ks][j] = P[q=l31][kv = ks*16 + hi*8 + j]; all plswap operands are
    // distinct live values (safe).
    bf16x8 pf[4];
    {
      uint a0 = cvtpk(p0[0], p0[1]),  b0 = cvtpk(p0[4], p0[5]);   plswap(a0, b0);
      uint a1 = cvtpk(p0[2], p0[3]),  b1 = cvtpk(p0[6], p0[7]);   plswap(a1, b1);
      uint4 u0 = {a0, a1, b0, b1};  pf[0] = *(bf16x8*)&u0;
      uint a2 = cvtpk(p0[8], p0[9]),  b2 = cvtpk(p0[12], p0[13]); plswap(a2, b2);
      uint a3 = cvtpk(p0[10], p0[11]),b3 = cvtpk(p0[14], p0[15]); plswap(a3, b3);
      uint4 u1 = {a2, a3, b2, b3};  pf[1] = *(bf16x8*)&u1;
      uint a4 = cvtpk(p1[0], p1[1]),  b4 = cvtpk(p1[4], p1[5]);   plswap(a4, b4);
      uint a5 = cvtpk(p1[2], p1[3]),  b5 = cvtpk(p1[6], p1[7]);   plswap(a5, b5);
      uint4 u2 = {a4, a5, b4, b5};  pf[2] = *(bf16x8*)&u2;
      uint a6 = cvtpk(p1[8], p1[9]),  b6 = cvtpk(p1[12], p1[13]); plswap(a6, b6);
      uint a7 = cvtpk(p1[10], p1[11]),b7 = cvtpk(p1[14], p1[15]); plswap(a7, b7);
      uint4 u3 = {a6, a7, b6, b7};  pf[3] = *(bf16x8*)&u3;
    }

    // ---- PV: O^T += V^T P^T : 16 MFMA (A = V^T rows=d, B = P rows=q)
    const int vbU = (t & 1) ? OFF_V1U : OFF_V0U;
    __builtin_amdgcn_s_setprio(1);
#pragma unroll
    for (int ks = 0; ks < 4; ++ks) {
      int cc = ((2 * ks + hi) ^ vx) << 3;
#pragma unroll
      for (int dt = 0; dt < 4; ++dt) {
        bf16x8 vf = *(const bf16x8*)&SM[vbU + (dt * 32 + l31) * 64 + cc];
        oacc[dt] = __builtin_amdgcn_mfma_f32_32x32x16_bf16(vf, pf[ks], oacc[dt], 0, 0, 0);
      }
    }
    __builtin_amdgcn_s_setprio(0);
  }

  // ---- epilogue: O^T -> per-wave LDS transpose -> coalesced global store
  float linv = 1.0f / l_i;
  const int RB = w * 4096;
#pragma unroll
  for (int dt = 0; dt < 4; ++dt)
#pragma unroll
    for (int r = 0; r < 16; ++r) {
      int d = dt * 32 + (r & 3) + 8 * (r >> 2) + 4 * hi;
      SM[RB + l31 * 128 + (((d >> 3) ^ (l31 & 15)) << 3) + (d & 7)] =
          f2bf(oacc[dt][r] * linv);
    }
  {
    const int r4 = lane >> 4, c16 = lane & 15;
#pragma unroll
    for (int i = 0; i < 8; ++i) {
      int qq = i * 4 + r4;
      uint4 v = *(const uint4*)&SM[RB + qq * 128 + ((c16 ^ (qq & 15)) << 3)];
      *(uint4*)(O + (size_t)(q0 + w * 32 + qq) * DIM + h * HD + c16 * 8) = v;
    }
  }
}

// ---------------- launcher ----------------------------------------------------
extern "C" void kernel_launch(void* const* d_in, const int* in_sizes, int n_in,
                              void* d_out, int out_size, void* d_ws, size_t ws_size,
                              hipStream_t stream) {
  const float* x  = (const float*)d_in[0];
  const float* fc = (const float*)d_in[1];
  const float* fs = (const float*)d_in[2];
  const float* wq = (const float*)d_in[3];
  const float* wk = (const float*)d_in[4];
  const float* wv = (const float*)d_in[5];
  const float* wo = (const float*)d_in[6];
  float* out = (float*)d_out;

  // ws (bf16 elems): xb | wT (wqT then wkT then wvT contiguous: 6144 x 4096)
  //                  | qb | kb | vT  (vT = kb + SEQ*KVDIM)
  ushort* xb   = (ushort*)d_ws;
  ushort* wT   = xb   + (size_t)SEQ * DIM;      // 6144 x 4096 (wq | wk | wv)
  ushort* wkvT = wT   + (size_t)DIM * DIM;      // = rows 4096.. of wT
  ushort* qb   = wkvT + (size_t)2048 * DIM;
  ushort* kb   = qb   + (size_t)SEQ * DIM;
  ushort* vT   = kb   + (size_t)SEQ * KVDIM;    // 1024 x 2048
  ushort* ab   = qb;                            // attention out aliases Q

  dim3 blk(256);

  convert_f32_bf16<<<(SEQ * DIM) / 2048, blk, 0, stream>>>(x, xb);
  transpose_w<<<dim3(DIM / 32, DIM / 32), blk, 0, stream>>>(wq, wT, DIM, DIM);
  transpose_w<<<dim3(KVDIM / 32, DIM / 32), blk, 0, stream>>>(wk, wkvT, DIM, KVDIM);
  transpose_w<<<dim3(KVDIM / 32, DIM / 32), blk, 0, stream>>>(wv, wkvT + (size_t)KVDIM * DIM, DIM, KVDIM);

  // fused Q/K/V projection: N = 6144 (cols: 0..4095 Q, ..5119 K, ..6143 V^T)
  gemm_bt<<<dim3(6144 / 128, SEQ / 128), blk, 0, stream>>>(xb, wT, qb, kb, SEQ, 6144, DIM, 2);

  rope_kernel<<<(SEQ * NH * 64) / 256, blk, 0, stream>>>(qb, fc, fs, 5);
  rope_kernel<<<(SEQ * NKV * 64) / 256, blk, 0, stream>>>(kb, fc, fs, 3);

  attn_mfma5<<<dim3(SEQ / 128, NH), blk, 0, stream>>>(qb, kb, vT, ab);

  // transpose wo into the (now dead) wqT region, then output projection
  transpose_w<<<dim3(DIM / 32, DIM / 32), blk, 0, stream>>>(wo, wT, DIM, DIM);
  gemm_bt<<<dim3(DIM / 128, SEQ / 128), blk, 0, stream>>>(ab, wT, out, nullptr, SEQ, DIM, DIM, 1);
}

// Round 5
// 538.197 us; speedup vs baseline: 1.2798x; 1.0042x over previous
//
#include <hip/hip_runtime.h>
#include <hip/hip_bf16.h>

#define SEQ   2048
#define DIM   4096
#define NH    32
#define NKV   8
#define HD    128
#define KVDIM 1024
#define SCALE 0.08838834764831845f

typedef __attribute__((ext_vector_type(8))) short bf16x8;
typedef __attribute__((ext_vector_type(4))) float f32x4;
typedef __attribute__((ext_vector_type(16))) float f32x16;

__device__ __forceinline__ ushort f2bf(float f) {  // RTN fp32 -> bf16 bits
  __hip_bfloat16 h = __float2bfloat16(f);
  return *reinterpret_cast<ushort*>(&h);
}

// async global->LDS, 16B per lane; LDS dest = wave-uniform base + lane*16
typedef const __attribute__((address_space(1))) uint* gas_ptr;
typedef __attribute__((address_space(3))) uint* las_ptr;
__device__ __forceinline__ void async16(const ushort* g, ushort* l) {
  __builtin_amdgcn_global_load_lds((gas_ptr)g, (las_ptr)l, 16, 0, 0);
}

// v_cvt_pk_bf16_f32: D[15:0]=bf16(lo), D[31:16]=bf16(hi)
__device__ __forceinline__ uint cvtpk(float lo, float hi) {
  uint r;
  asm("v_cvt_pk_bf16_f32 %0, %1, %2" : "=v"(r) : "v"(lo), "v"(hi));
  return r;
}
// v_permlane32_swap_b32 (dst.hi <-> src.lo): newA = {A.lo, B.lo}, newB = {A.hi, B.hi}
// NOTE: operands MUST be distinct live values (distinct VGPRs).
__device__ __forceinline__ void plswap(uint& a, uint& b) {
  asm("v_permlane32_swap_b32 %0, %1" : "+v"(a), "+v"(b));
}

// ---------------- fp32 -> bf16 elementwise (x) --------------------------------
__global__ __launch_bounds__(256) void convert_f32_bf16(
    const float* __restrict__ in, ushort* __restrict__ out)
{
  int i = (blockIdx.x * 256 + threadIdx.x) * 8;
  float4 a = *(const float4*)(in + i);
  float4 b = *(const float4*)(in + i + 4);
  uint4 u;
  u.x = (uint)f2bf(a.x) | ((uint)f2bf(a.y) << 16);
  u.y = (uint)f2bf(a.z) | ((uint)f2bf(a.w) << 16);
  u.z = (uint)f2bf(b.x) | ((uint)f2bf(b.y) << 16);
  u.w = (uint)f2bf(b.z) | ((uint)f2bf(b.w) << 16);
  *(uint4*)(out + i) = u;
}

// ---------------- W[K][N] fp32 -> WT[N][K] bf16 (32x32 LDS tiles) -------------
__global__ __launch_bounds__(256) void transpose_w(
    const float* __restrict__ W, ushort* __restrict__ WT, int K, int N)
{
  __shared__ float t[32][33];
  const int k0 = blockIdx.y * 32, n0 = blockIdx.x * 32;
  const int tid = threadIdx.x;
  {
    int r = tid >> 3, c0 = (tid & 7) * 4;
    float4 v = *(const float4*)(W + (size_t)(k0 + r) * N + n0 + c0);
    t[r][c0] = v.x; t[r][c0 + 1] = v.y; t[r][c0 + 2] = v.z; t[r][c0 + 3] = v.w;
  }
  __syncthreads();
  {
    int n = tid >> 3, kc = (tid & 7) * 4;
    ushort4 u;
    u.x = f2bf(t[kc + 0][n]); u.y = f2bf(t[kc + 1][n]);
    u.z = f2bf(t[kc + 2][n]); u.w = f2bf(t[kc + 3][n]);
    *(ushort4*)(WT + (size_t)(n0 + n) * K + k0 + kc) = u;
  }
}

// ---------------- GEMM v3: C = A[MxK] * BT[NxK]^T, bf16 -----------------------
// 128x128 tile, BK=32, 4 waves 2x2, TRIPLE-buffered LDS (48 KiB -> 3 blk/CU),
// counted vmcnt (T4): per K-step  s_waitcnt vmcnt(4) -> raw s_barrier ->
// STAGE(t+2) -> ds_read(t) -> 16 MFMA.  Loads for tiles t+1,t+2 stay in
// flight ACROSS barriers; vmcnt never drains to 0 in the main loop (last
// iter peeled with vmcnt(0)).  Race-safety: every wave waits its own tile-t
// loads (vmcnt<=4) before the barrier => at rendezvous ALL tile-t loads
// landed; STAGE targets buf (t+2)%3 != read buf t%3; ds_reads cannot sink
// past their consuming MFMAs, so they complete before the next barrier.
// Chunk swizzle mod-4 both-sides (64 B rows): stage src chunk (c^(r&3)) ->
// slot c; read slot quad^(row&3).  <=2-way bank aliasing (free, m136).
// mode 0: bf16 C stride N. mode 1: fp32 C stride N.
// mode 2: fused QKV: col<4096 -> qb (stride DIM); col<5120 -> kb (stride
//         KVDIM); else vT[(col-5120)*SEQ + m]  (Cv=qb, C2v=kb).
__device__ __forceinline__ void stage_tile(
    const ushort* __restrict__ A, const ushort* __restrict__ BT,
    ushort* as, ushort* bs, int m0, int n0, int K, int k0, int w, int lane)
{
  const int rl = lane >> 2;                 // 0..15 row within 16-row chunk
  const int cl = lane & 3;                  // 16B chunk within 64B row
#pragma unroll
  for (int i = 0; i < 2; ++i) {
    const int rb = i * 64 + w * 16;         // wave-uniform LDS row base
    const int r  = rb + rl;
    const int sc = (cl ^ (r & 3)) << 3;     // pre-swizzled source chunk
    async16(A  + (size_t)(m0 + r) * K + k0 + sc, as + rb * 32);
    async16(BT + (size_t)(n0 + r) * K + k0 + sc, bs + rb * 32);
  }                                          // 4 vmem ops per thread
}

__global__ __launch_bounds__(256) void gemm_bt(
    const ushort* __restrict__ A, const ushort* __restrict__ BT,
    void* __restrict__ Cv, void* __restrict__ C2v,
    int M, int N, int K, int mode)
{
  __shared__ __align__(16) ushort As[3][128 * 32];
  __shared__ __align__(16) ushort Bs[3][128 * 32];

  const int tid  = threadIdx.x;
  const int lane = tid & 63;
  const int w    = tid >> 6;
  const int wr = w >> 1, wc = w & 1;
  const int quad = lane >> 4, l16 = lane & 15;
  const int m0 = blockIdx.y * 128, n0 = blockIdx.x * 128;

  f32x4 acc[4][4];
#pragma unroll
  for (int bm = 0; bm < 4; ++bm)
#pragma unroll
    for (int bn = 0; bn < 4; ++bn)
      acc[bm][bn] = (f32x4){0.f, 0.f, 0.f, 0.f};

  const int nt = K >> 5;
  // prologue: tiles 0 and 1 in flight
  stage_tile(A, BT, As[0], Bs[0], m0, n0, K, 0, w, lane);
  stage_tile(A, BT, As[1], Bs[1], m0, n0, K, 32, w, lane);

  for (int t = 0; t < nt; ++t) {
    if (t + 1 < nt) {
      asm volatile("s_waitcnt vmcnt(4)" ::: "memory");   // tile t landed (own)
    } else {
      asm volatile("s_waitcnt vmcnt(0)" ::: "memory");   // final: drain
    }
    __builtin_amdgcn_s_barrier();                        // all waves' tile t in
    asm volatile("" ::: "memory");
    if (t + 2 < nt)
      stage_tile(A, BT, As[(t + 2) % 3], Bs[(t + 2) % 3],
                 m0, n0, K, (t + 2) * 32, w, lane);

    const ushort* as = As[t % 3];
    const ushort* bs = Bs[t % 3];
    bf16x8 af[4], bf[4];
#pragma unroll
    for (int bm = 0; bm < 4; ++bm) {
      const int row = wr * 64 + bm * 16 + l16;
      af[bm] = *(const bf16x8*)&as[row * 32 + ((quad ^ (row & 3)) << 3)];
    }
#pragma unroll
    for (int bn = 0; bn < 4; ++bn) {
      const int row = wc * 64 + bn * 16 + l16;
      bf[bn] = *(const bf16x8*)&bs[row * 32 + ((quad ^ (row & 3)) << 3)];
    }
    __builtin_amdgcn_s_setprio(1);
#pragma unroll
    for (int bm = 0; bm < 4; ++bm)
#pragma unroll
      for (int bn = 0; bn < 4; ++bn)
        acc[bm][bn] = __builtin_amdgcn_mfma_f32_16x16x32_bf16(
            af[bm], bf[bn], acc[bm][bn], 0, 0, 0);
    __builtin_amdgcn_s_setprio(0);
  }

  // C/D layout: row = quad*4 + i, col = l16 (m89-verified)
  if (mode == 0) {
    ushort* C = (ushort*)Cv;
#pragma unroll
    for (int bm = 0; bm < 4; ++bm) {
      int rbase = m0 + wr * 64 + bm * 16 + quad * 4;
#pragma unroll
      for (int bn = 0; bn < 4; ++bn) {
        int col = n0 + wc * 64 + bn * 16 + l16;
#pragma unroll
        for (int i = 0; i < 4; ++i)
          C[(size_t)(rbase + i) * N + col] = f2bf(acc[bm][bn][i]);
      }
    }
  } else if (mode == 1) {
    float* C = (float*)Cv;
#pragma unroll
    for (int bm = 0; bm < 4; ++bm) {
      int rbase = m0 + wr * 64 + bm * 16 + quad * 4;
#pragma unroll
      for (int bn = 0; bn < 4; ++bn) {
        int col = n0 + wc * 64 + bn * 16 + l16;
#pragma unroll
        for (int i = 0; i < 4; ++i)
          C[(size_t)(rbase + i) * N + col] = acc[bm][bn][i];
      }
    }
  } else {  // mode 2: fused QKV
    if (n0 < 4096) {
      ushort* C = (ushort*)Cv;   // qb natural, stride DIM
#pragma unroll
      for (int bm = 0; bm < 4; ++bm) {
        int rbase = m0 + wr * 64 + bm * 16 + quad * 4;
#pragma unroll
        for (int bn = 0; bn < 4; ++bn) {
          int col = n0 + wc * 64 + bn * 16 + l16;
#pragma unroll
          for (int i = 0; i < 4; ++i)
            C[(size_t)(rbase + i) * DIM + col] = f2bf(acc[bm][bn][i]);
        }
      }
    } else if (n0 < 5120) {
      ushort* C = (ushort*)C2v;  // kb natural, stride KVDIM
#pragma unroll
      for (int bm = 0; bm < 4; ++bm) {
        int rbase = m0 + wr * 64 + bm * 16 + quad * 4;
#pragma unroll
        for (int bn = 0; bn < 4; ++bn) {
          int col = n0 + wc * 64 + bn * 16 + l16 - 4096;
#pragma unroll
          for (int i = 0; i < 4; ++i)
            C[(size_t)(rbase + i) * KVDIM + col] = f2bf(acc[bm][bn][i]);
        }
      }
    } else {
      ushort* C2 = (ushort*)C2v + (size_t)SEQ * KVDIM; // vT[(col-5120)*SEQ + m]
#pragma unroll
      for (int bm = 0; bm < 4; ++bm) {
        int rbase = m0 + wr * 64 + bm * 16 + quad * 4;
#pragma unroll
        for (int bn = 0; bn < 4; ++bn) {
          int col = n0 + wc * 64 + bn * 16 + l16 - 5120;
          ushort4 u;
          u.x = f2bf(acc[bm][bn][0]); u.y = f2bf(acc[bm][bn][1]);
          u.z = f2bf(acc[bm][bn][2]); u.w = f2bf(acc[bm][bn][3]);
          *(ushort4*)(C2 + (size_t)col * SEQ + rbase) = u;
        }
      }
    }
  }
}

// ---------------- RoPE (interleaved pairs), in place on bf16 ------------------
__device__ __forceinline__ float bfhi(uint u) {
  union { uint i; float f; } v; v.i = u & 0xffff0000u; return v.f;
}
__device__ __forceinline__ float bflo(uint u) {
  union { uint i; float f; } v; v.i = u << 16; return v.f;
}
__global__ __launch_bounds__(256) void rope_kernel(
    ushort* __restrict__ t, const float* __restrict__ cosb,
    const float* __restrict__ sinb, int shift)
{
  int idx = blockIdx.x * 256 + threadIdx.x;
  int p  = idx & 63;
  int sh = idx >> 6;
  int s  = sh >> shift;
  uint* bp = (uint*)(t + ((size_t)sh << 7)) + p;
  uint u = *bp;
  float t1 = bflo(u), t2 = bfhi(u);
  float c  = cosb[(s << 6) + p];
  float sv = sinb[(s << 6) + p];
  float o1 = t1 * c - t2 * sv;
  float o2 = t1 * sv + t2 * c;
  *bp = ((uint)f2bf(o1)) | (((uint)f2bf(o2)) << 16);
}

// ---------------- MFMA flash attention v5: 32x32 swapped-QK, in-reg softmax ---
// Per wave: 32 q-rows. S^T = mfma(K,Q): lane owns q = lane&31 entirely.
// P in registers (cvt_pk + permlane32_swap with DISTINCT values, T12).
// PV: O^T = V^T * P^T. Defer-max THR=8 (T13). DMA staging, XOR chunk swizzle
// both-sides. K single-buffer, V^T double-buffer, prefetch after barrier B.
#define OFF_V0U 8192
#define OFF_V1U 16384
#define NT (SEQ / 64)

__device__ __forceinline__ void stage_K(const ushort* __restrict__ K, ushort* SM,
                                        int w, int lane, int kb, int kvh) {
  const int r4 = lane >> 4, c16 = lane & 15;
#pragma unroll
  for (int j = 0; j < 4; ++j) {
    int rb = w * 16 + j * 4, row = rb + r4;
    int c = c16 ^ (row & 15);
    async16(K + (size_t)(kb + row) * KVDIM + kvh * HD + c * 8, &SM[rb * 128]);
  }
}
__device__ __forceinline__ void stage_V(const ushort* __restrict__ VT, ushort* SMv,
                                        int w, int lane, int kb, int kvh) {
  const int r8 = lane >> 3, c8 = lane & 7;
#pragma unroll
  for (int j = 0; j < 4; ++j) {
    int rb = w * 32 + j * 8, row = rb + r8;
    int c = c8 ^ (row & 7);
    async16(VT + (size_t)(kvh * 128 + row) * SEQ + kb + c * 8, &SMv[rb * 64]);
  }
}

__global__ __launch_bounds__(256, 2) void attn_mfma5(
    const ushort* __restrict__ Q, const ushort* __restrict__ K,
    const ushort* __restrict__ VT, ushort* __restrict__ O)
{
  __shared__ __align__(16) ushort SM[24576];   // 49152 B

  const int tid = threadIdx.x, lane = tid & 63, w = tid >> 6;
  const int l31 = lane & 31, hi = lane >> 5;
  const int kx = l31 & 15;          // row&15 for K/Q reads (rows ≡ l31 mod 32)
  const int vx = lane & 7;          // row&7 for V reads
  const int h = blockIdx.y, kvh = h >> 2;
  const int q0 = blockIdx.x * 128;

  // ---- stage Q (128 rows x 256B, swizzled chunks) via DMA into [0,16384)
  {
    const int r4 = lane >> 4, c16 = lane & 15;
#pragma unroll
    for (int j = 0; j < 8; ++j) {
      int rb = w * 32 + j * 4, row = rb + r4;
      int c = c16 ^ (row & 15);
      async16(Q + (size_t)(q0 + row) * DIM + h * HD + c * 8, &SM[rb * 128]);
    }
  }
  __syncthreads();

  // ---- Q fragments in registers: B-operand, col(q) = l31
  bf16x8 qf[8];
#pragma unroll
  for (int ks = 0; ks < 8; ++ks) {
    int cc = ((2 * ks + hi) ^ kx) << 3;
    qf[ks] = *(const bf16x8*)&SM[(w * 32 + l31) * 128 + cc];
  }
  __syncthreads();   // all Q reads done before K/V DMA lands

  // ---- prologue: stage K(0), VT(0)
  stage_K(K, SM, w, lane, 0, kvh);
  stage_V(VT, &SM[OFF_V0U], w, lane, 0, kvh);

  f32x16 oacc[4];
#pragma unroll
  for (int dt = 0; dt < 4; ++dt)
#pragma unroll
    for (int r = 0; r < 16; ++r) oacc[dt][r] = 0.f;
  float m_i = -1e30f, l_i = 0.f;

  for (int t = 0; t < NT; ++t) {
    __syncthreads();   // A: K(t)/VT(t) staging drained (vmcnt0 at barrier)

    // ---- S^T = K Q^T : 16 MFMA 32x32x16 (A = K rows, B = Q rows)
    f32x16 s0, s1;
#pragma unroll
    for (int r = 0; r < 16; ++r) { s0[r] = 0.f; s1[r] = 0.f; }
    __builtin_amdgcn_s_setprio(1);
#pragma unroll
    for (int ks = 0; ks < 8; ++ks) {
      int cc = ((2 * ks + hi) ^ kx) << 3;
      bf16x8 k0 = *(const bf16x8*)&SM[l31 * 128 + cc];
      bf16x8 k1 = *(const bf16x8*)&SM[(32 + l31) * 128 + cc];
      s0 = __builtin_amdgcn_mfma_f32_32x32x16_bf16(k0, qf[ks], s0, 0, 0, 0);
      s1 = __builtin_amdgcn_mfma_f32_32x32x16_bf16(k1, qf[ks], s1, 0, 0, 0);
    }
    __builtin_amdgcn_s_setprio(0);

    __syncthreads();   // B: all waves done reading K buffer

    // ---- prefetch next K / VT (latency hides under softmax + PV)
    if (t + 1 < NT) {
      stage_K(K, SM, w, lane, (t + 1) * 64, kvh);
      stage_V(VT, &SM[((t + 1) & 1) ? OFF_V1U : OFF_V0U], w, lane, (t + 1) * 64, kvh);
    }

    // ---- in-register online softmax (lane owns q = l31; kv split across hi)
    float tm[16];
#pragma unroll
    for (int i = 0; i < 16; ++i) tm[i] = fmaxf(s0[i], s1[i]);
#pragma unroll
    for (int d = 8; d >= 1; d >>= 1)
#pragma unroll
      for (int i = 0; i < 8; ++i) if (i < d) tm[i] = fmaxf(tm[i], tm[i + d]);
    float lm = fmaxf(tm[0], __shfl_xor(tm[0], 32));   // cross-half exchange
    float lmS = lm * SCALE;
    float mn;
    if (__any(lmS > m_i + 8.0f)) {        // rescale path (defer-max, THR=8)
      mn = fmaxf(m_i, lmS);
      float al = __expf(m_i - mn);
      m_i = mn; l_i *= al;
#pragma unroll
      for (int dt = 0; dt < 4; ++dt)
#pragma unroll
        for (int r = 0; r < 16; ++r) oacc[dt][r] *= al;
    } else mn = m_i;

    float p0[16], p1[16];
#pragma unroll
    for (int r = 0; r < 16; ++r) p0[r] = __expf(fmaf(s0[r], SCALE, -mn));
#pragma unroll
    for (int r = 0; r < 16; ++r) p1[r] = __expf(fmaf(s1[r], SCALE, -mn));
    {
      float ts[16];
#pragma unroll
      for (int i = 0; i < 16; ++i) ts[i] = p0[i] + p1[i];
#pragma unroll
      for (int d = 8; d >= 1; d >>= 1)
#pragma unroll
        for (int i = 0; i < 8; ++i) if (i < d) ts[i] += ts[i + d];
      l_i += ts[0] + __shfl_xor(ts[0], 32);           // cross-half exchange
    }

    // ---- P -> bf16 PV B-operand frags (T12): 16 cvt_pk + 8 permlane32_swap
    bf16x8 pf[4];
    {
      uint a0 = cvtpk(p0[0], p0[1]),  b0 = cvtpk(p0[4], p0[5]);   plswap(a0, b0);
      uint a1 = cvtpk(p0[2], p0[3]),  b1 = cvtpk(p0[6], p0[7]);   plswap(a1, b1);
      uint4 u0 = {a0, a1, b0, b1};  pf[0] = *(bf16x8*)&u0;
      uint a2 = cvtpk(p0[8], p0[9]),  b2 = cvtpk(p0[12], p0[13]); plswap(a2, b2);
      uint a3 = cvtpk(p0[10], p0[11]),b3 = cvtpk(p0[14], p0[15]); plswap(a3, b3);
      uint4 u1 = {a2, a3, b2, b3};  pf[1] = *(bf16x8*)&u1;
      uint a4 = cvtpk(p1[0], p1[1]),  b4 = cvtpk(p1[4], p1[5]);   plswap(a4, b4);
      uint a5 = cvtpk(p1[2], p1[3]),  b5 = cvtpk(p1[6], p1[7]);   plswap(a5, b5);
      uint4 u2 = {a4, a5, b4, b5};  pf[2] = *(bf16x8*)&u2;
      uint a6 = cvtpk(p1[8], p1[9]),  b6 = cvtpk(p1[12], p1[13]); plswap(a6, b6);
      uint a7 = cvtpk(p1[10], p1[11]),b7 = cvtpk(p1[14], p1[15]); plswap(a7, b7);
      uint4 u3 = {a6, a7, b6, b7};  pf[3] = *(bf16x8*)&u3;
    }

    // ---- PV: O^T += V^T P^T : 16 MFMA (A = V^T rows=d, B = P rows=q)
    const int vbU = (t & 1) ? OFF_V1U : OFF_V0U;
    __builtin_amdgcn_s_setprio(1);
#pragma unroll
    for (int ks = 0; ks < 4; ++ks) {
      int cc = ((2 * ks + hi) ^ vx) << 3;
#pragma unroll
      for (int dt = 0; dt < 4; ++dt) {
        bf16x8 vf = *(const bf16x8*)&SM[vbU + (dt * 32 + l31) * 64 + cc];
        oacc[dt] = __builtin_amdgcn_mfma_f32_32x32x16_bf16(vf, pf[ks], oacc[dt], 0, 0, 0);
      }
    }
    __builtin_amdgcn_s_setprio(0);
  }

  // ---- epilogue: O^T -> per-wave LDS transpose -> coalesced global store
  float linv = 1.0f / l_i;
  const int RB = w * 4096;
#pragma unroll
  for (int dt = 0; dt < 4; ++dt)
#pragma unroll
    for (int r = 0; r < 16; ++r) {
      int d = dt * 32 + (r & 3) + 8 * (r >> 2) + 4 * hi;
      SM[RB + l31 * 128 + (((d >> 3) ^ (l31 & 15)) << 3) + (d & 7)] =
          f2bf(oacc[dt][r] * linv);
    }
  {
    const int r4 = lane >> 4, c16 = lane & 15;
#pragma unroll
    for (int i = 0; i < 8; ++i) {
      int qq = i * 4 + r4;
      uint4 v = *(const uint4*)&SM[RB + qq * 128 + ((c16 ^ (qq & 15)) << 3)];
      *(uint4*)(O + (size_t)(q0 + w * 32 + qq) * DIM + h * HD + c16 * 8) = v;
    }
  }
}

// ---------------- launcher ----------------------------------------------------
extern "C" void kernel_launch(void* const* d_in, const int* in_sizes, int n_in,
                              void* d_out, int out_size, void* d_ws, size_t ws_size,
                              hipStream_t stream) {
  const float* x  = (const float*)d_in[0];
  const float* fc = (const float*)d_in[1];
  const float* fs = (const float*)d_in[2];
  const float* wq = (const float*)d_in[3];
  const float* wk = (const float*)d_in[4];
  const float* wv = (const float*)d_in[5];
  const float* wo = (const float*)d_in[6];
  float* out = (float*)d_out;

  // ws (bf16 elems): xb | wT (wqT then wkT then wvT contiguous: 6144 x 4096)
  //                  | qb | kb | vT  (vT = kb + SEQ*KVDIM)
  ushort* xb   = (ushort*)d_ws;
  ushort* wT   = xb   + (size_t)SEQ * DIM;      // 6144 x 4096 (wq | wk | wv)
  ushort* wkvT = wT   + (size_t)DIM * DIM;      // = rows 4096.. of wT
  ushort* qb   = wkvT + (size_t)2048 * DIM;
  ushort* kb   = qb   + (size_t)SEQ * DIM;
  ushort* vT   = kb   + (size_t)SEQ * KVDIM;    // 1024 x 2048
  ushort* ab   = qb;                            // attention out aliases Q

  dim3 blk(256);

  convert_f32_bf16<<<(SEQ * DIM) / 2048, blk, 0, stream>>>(x, xb);
  transpose_w<<<dim3(DIM / 32, DIM / 32), blk, 0, stream>>>(wq, wT, DIM, DIM);
  transpose_w<<<dim3(KVDIM / 32, DIM / 32), blk, 0, stream>>>(wk, wkvT, DIM, KVDIM);
  transpose_w<<<dim3(KVDIM / 32, DIM / 32), blk, 0, stream>>>(wv, wkvT + (size_t)KVDIM * DIM, DIM, KVDIM);

  // fused Q/K/V projection: N = 6144 (cols: 0..4095 Q, ..5119 K, ..6143 V^T)
  gemm_bt<<<dim3(6144 / 128, SEQ / 128), blk, 0, stream>>>(xb, wT, qb, kb, SEQ, 6144, DIM, 2);

  rope_kernel<<<(SEQ * NH * 64) / 256, blk, 0, stream>>>(qb, fc, fs, 5);
  rope_kernel<<<(SEQ * NKV * 64) / 256, blk, 0, stream>>>(kb, fc, fs, 3);

  attn_mfma5<<<dim3(SEQ / 128, NH), blk, 0, stream>>>(qb, kb, vT, ab);

  // transpose wo into the (now dead) wqT region, then output projection
  transpose_w<<<dim3(DIM / 32, DIM / 32), blk, 0, stream>>>(wo, wT, DIM, DIM);
  gemm_bt<<<dim3(DIM / 128, SEQ / 128), blk, 0, stream>>>(ab, wT, out, nullptr, SEQ, DIM, DIM, 1);
}

// Round 6
// 515.525 us; speedup vs baseline: 1.3361x; 1.0440x over previous
//
#include <hip/hip_runtime.h>
#include <hip/hip_bf16.h>

#define SEQ   2048
#define DIM   4096
#define NH    32
#define NKV   8
#define HD    128
#define KVDIM 1024
#define SCALE 0.08838834764831845f

typedef __attribute__((ext_vector_type(8))) short bf16x8;
typedef __attribute__((ext_vector_type(4))) float f32x4;
typedef __attribute__((ext_vector_type(16))) float f32x16;

__device__ __forceinline__ ushort f2bf(float f) {  // RTN fp32 -> bf16 bits
  __hip_bfloat16 h = __float2bfloat16(f);
  return *reinterpret_cast<ushort*>(&h);
}

// async global->LDS, 16B per lane; LDS dest = wave-uniform base + lane*16
typedef const __attribute__((address_space(1))) uint* gas_ptr;
typedef __attribute__((address_space(3))) uint* las_ptr;
__device__ __forceinline__ void async16(const ushort* g, ushort* l) {
  __builtin_amdgcn_global_load_lds((gas_ptr)g, (las_ptr)l, 16, 0, 0);
}

// v_cvt_pk_bf16_f32: D[15:0]=bf16(lo), D[31:16]=bf16(hi)
__device__ __forceinline__ uint cvtpk(float lo, float hi) {
  uint r;
  asm("v_cvt_pk_bf16_f32 %0, %1, %2" : "=v"(r) : "v"(lo), "v"(hi));
  return r;
}
// v_permlane32_swap_b32 (dst.hi <-> src.lo): newA = {A.lo, B.lo}, newB = {A.hi, B.hi}
// NOTE: operands MUST be distinct live values (distinct VGPRs).
__device__ __forceinline__ void plswap(uint& a, uint& b) {
  asm("v_permlane32_swap_b32 %0, %1" : "+v"(a), "+v"(b));
}

// ---------------- fp32 -> bf16 elementwise (x) --------------------------------
__global__ __launch_bounds__(256) void convert_f32_bf16(
    const float* __restrict__ in, ushort* __restrict__ out)
{
  int i = (blockIdx.x * 256 + threadIdx.x) * 8;
  float4 a = *(const float4*)(in + i);
  float4 b = *(const float4*)(in + i + 4);
  uint4 u;
  u.x = (uint)f2bf(a.x) | ((uint)f2bf(a.y) << 16);
  u.y = (uint)f2bf(a.z) | ((uint)f2bf(a.w) << 16);
  u.z = (uint)f2bf(b.x) | ((uint)f2bf(b.y) << 16);
  u.w = (uint)f2bf(b.z) | ((uint)f2bf(b.w) << 16);
  *(uint4*)(out + i) = u;
}

// ---------------- W[K][N] fp32 -> WT[N][K] bf16 (32x32 LDS tiles) -------------
__global__ __launch_bounds__(256) void transpose_w(
    const float* __restrict__ W, ushort* __restrict__ WT, int K, int N)
{
  __shared__ float t[32][33];
  const int k0 = blockIdx.y * 32, n0 = blockIdx.x * 32;
  const int tid = threadIdx.x;
  {
    int r = tid >> 3, c0 = (tid & 7) * 4;
    float4 v = *(const float4*)(W + (size_t)(k0 + r) * N + n0 + c0);
    t[r][c0] = v.x; t[r][c0 + 1] = v.y; t[r][c0 + 2] = v.z; t[r][c0 + 3] = v.w;
  }
  __syncthreads();
  {
    int n = tid >> 3, kc = (tid & 7) * 4;
    ushort4 u;
    u.x = f2bf(t[kc + 0][n]); u.y = f2bf(t[kc + 1][n]);
    u.z = f2bf(t[kc + 2][n]); u.w = f2bf(t[kc + 3][n]);
    *(ushort4*)(WT + (size_t)(n0 + n) * K + k0 + kc) = u;
  }
}

// ---------------- GEMM v3b: C = A[MxK] * BT[NxK]^T, bf16 ----------------------
// 128x128 tile, BK=32, 4 waves 2x2, TRIPLE-buffered LDS (48 KiB -> 3 blk/CU),
// counted vmcnt (T4): per K-step  s_waitcnt vmcnt(4) -> raw s_barrier ->
// STAGE(t+2) -> ds_read(t) -> 16 MFMA.  Loads for tiles t+1,t+2 stay in
// flight ACROSS barriers; vmcnt never drains to 0 in the main loop.
// Swizzle (64 B rows, 4 chunk slots; bank = 16*(row&1) + 4*slot):
//   slot = chunk ^ ((row>>1)&3)  -> each (parity,slot) cell holds exactly 2
//   of the 16 rows in a read group => 2-way aliasing = FREE (m136).
//   [R5's chunk^(row&3) was a 4-way conflict: rows r,r+4,r+8,r+12 collide.]
// Both-sides: stage source chunk = cl ^ ((r>>1)&3), read slot = quad ^ ((row>>1)&3).
// mode 0: bf16 C stride N. mode 1: fp32 C stride N.
// mode 2: fused QKV: col<4096 -> qb (stride DIM); col<5120 -> kb (stride
//         KVDIM); else vT[(col-5120)*SEQ + m]  (Cv=qb, C2v=kb).
__device__ __forceinline__ void stage_tile(
    const ushort* __restrict__ A, const ushort* __restrict__ BT,
    ushort* as, ushort* bs, int m0, int n0, int K, int k0, int w, int lane)
{
  const int rl = lane >> 2;                 // 0..15 row within 16-row chunk
  const int cl = lane & 3;                  // 16B chunk within 64B row
#pragma unroll
  for (int i = 0; i < 2; ++i) {
    const int rb = i * 64 + w * 16;         // wave-uniform LDS row base
    const int r  = rb + rl;
    const int sc = (cl ^ ((r >> 1) & 3)) << 3;   // pre-swizzled source chunk
    async16(A  + (size_t)(m0 + r) * K + k0 + sc, as + rb * 32);
    async16(BT + (size_t)(n0 + r) * K + k0 + sc, bs + rb * 32);
  }                                          // 4 vmem ops per thread
}

__global__ __launch_bounds__(256) void gemm_bt(
    const ushort* __restrict__ A, const ushort* __restrict__ BT,
    void* __restrict__ Cv, void* __restrict__ C2v,
    int M, int N, int K, int mode)
{
  __shared__ __align__(16) ushort As[3][128 * 32];
  __shared__ __align__(16) ushort Bs[3][128 * 32];

  const int tid  = threadIdx.x;
  const int lane = tid & 63;
  const int w    = tid >> 6;
  const int wr = w >> 1, wc = w & 1;
  const int quad = lane >> 4, l16 = lane & 15;
  const int m0 = blockIdx.y * 128, n0 = blockIdx.x * 128;

  f32x4 acc[4][4];
#pragma unroll
  for (int bm = 0; bm < 4; ++bm)
#pragma unroll
    for (int bn = 0; bn < 4; ++bn)
      acc[bm][bn] = (f32x4){0.f, 0.f, 0.f, 0.f};

  const int nt = K >> 5;
  // prologue: tiles 0 and 1 in flight
  stage_tile(A, BT, As[0], Bs[0], m0, n0, K, 0, w, lane);
  stage_tile(A, BT, As[1], Bs[1], m0, n0, K, 32, w, lane);

  for (int t = 0; t < nt; ++t) {
    if (t + 1 < nt) {
      asm volatile("s_waitcnt vmcnt(4)" ::: "memory");   // tile t landed (own)
    } else {
      asm volatile("s_waitcnt vmcnt(0)" ::: "memory");   // final: drain
    }
    __builtin_amdgcn_s_barrier();                        // all waves' tile t in
    asm volatile("" ::: "memory");
    if (t + 2 < nt)
      stage_tile(A, BT, As[(t + 2) % 3], Bs[(t + 2) % 3],
                 m0, n0, K, (t + 2) * 32, w, lane);

    const ushort* as = As[t % 3];
    const ushort* bs = Bs[t % 3];
    bf16x8 af[4], bf[4];
#pragma unroll
    for (int bm = 0; bm < 4; ++bm) {
      const int row = wr * 64 + bm * 16 + l16;
      af[bm] = *(const bf16x8*)&as[row * 32 + ((quad ^ ((row >> 1) & 3)) << 3)];
    }
#pragma unroll
    for (int bn = 0; bn < 4; ++bn) {
      const int row = wc * 64 + bn * 16 + l16;
      bf[bn] = *(const bf16x8*)&bs[row * 32 + ((quad ^ ((row >> 1) & 3)) << 3)];
    }
    __builtin_amdgcn_s_setprio(1);
#pragma unroll
    for (int bm = 0; bm < 4; ++bm)
#pragma unroll
      for (int bn = 0; bn < 4; ++bn)
        acc[bm][bn] = __builtin_amdgcn_mfma_f32_16x16x32_bf16(
            af[bm], bf[bn], acc[bm][bn], 0, 0, 0);
    __builtin_amdgcn_s_setprio(0);
  }

  // C/D layout: row = quad*4 + i, col = l16 (m89-verified)
  if (mode == 0) {
    ushort* C = (ushort*)Cv;
#pragma unroll
    for (int bm = 0; bm < 4; ++bm) {
      int rbase = m0 + wr * 64 + bm * 16 + quad * 4;
#pragma unroll
      for (int bn = 0; bn < 4; ++bn) {
        int col = n0 + wc * 64 + bn * 16 + l16;
#pragma unroll
        for (int i = 0; i < 4; ++i)
          C[(size_t)(rbase + i) * N + col] = f2bf(acc[bm][bn][i]);
      }
    }
  } else if (mode == 1) {
    float* C = (float*)Cv;
#pragma unroll
    for (int bm = 0; bm < 4; ++bm) {
      int rbase = m0 + wr * 64 + bm * 16 + quad * 4;
#pragma unroll
      for (int bn = 0; bn < 4; ++bn) {
        int col = n0 + wc * 64 + bn * 16 + l16;
#pragma unroll
        for (int i = 0; i < 4; ++i)
          C[(size_t)(rbase + i) * N + col] = acc[bm][bn][i];
      }
    }
  } else {  // mode 2: fused QKV
    if (n0 < 4096) {
      ushort* C = (ushort*)Cv;   // qb natural, stride DIM
#pragma unroll
      for (int bm = 0; bm < 4; ++bm) {
        int rbase = m0 + wr * 64 + bm * 16 + quad * 4;
#pragma unroll
        for (int bn = 0; bn < 4; ++bn) {
          int col = n0 + wc * 64 + bn * 16 + l16;
#pragma unroll
          for (int i = 0; i < 4; ++i)
            C[(size_t)(rbase + i) * DIM + col] = f2bf(acc[bm][bn][i]);
        }
      }
    } else if (n0 < 5120) {
      ushort* C = (ushort*)C2v;  // kb natural, stride KVDIM
#pragma unroll
      for (int bm = 0; bm < 4; ++bm) {
        int rbase = m0 + wr * 64 + bm * 16 + quad * 4;
#pragma unroll
        for (int bn = 0; bn < 4; ++bn) {
          int col = n0 + wc * 64 + bn * 16 + l16 - 4096;
#pragma unroll
          for (int i = 0; i < 4; ++i)
            C[(size_t)(rbase + i) * KVDIM + col] = f2bf(acc[bm][bn][i]);
        }
      }
    } else {
      ushort* C2 = (ushort*)C2v + (size_t)SEQ * KVDIM; // vT[(col-5120)*SEQ + m]
#pragma unroll
      for (int bm = 0; bm < 4; ++bm) {
        int rbase = m0 + wr * 64 + bm * 16 + quad * 4;
#pragma unroll
        for (int bn = 0; bn < 4; ++bn) {
          int col = n0 + wc * 64 + bn * 16 + l16 - 5120;
          ushort4 u;
          u.x = f2bf(acc[bm][bn][0]); u.y = f2bf(acc[bm][bn][1]);
          u.z = f2bf(acc[bm][bn][2]); u.w = f2bf(acc[bm][bn][3]);
          *(ushort4*)(C2 + (size_t)col * SEQ + rbase) = u;
        }
      }
    }
  }
}

// ---------------- RoPE (interleaved pairs), in place on bf16 ------------------
__device__ __forceinline__ float bfhi(uint u) {
  union { uint i; float f; } v; v.i = u & 0xffff0000u; return v.f;
}
__device__ __forceinline__ float bflo(uint u) {
  union { uint i; float f; } v; v.i = u << 16; return v.f;
}
__global__ __launch_bounds__(256) void rope_kernel(
    ushort* __restrict__ t, const float* __restrict__ cosb,
    const float* __restrict__ sinb, int shift)
{
  int idx = blockIdx.x * 256 + threadIdx.x;
  int p  = idx & 63;
  int sh = idx >> 6;
  int s  = sh >> shift;
  uint* bp = (uint*)(t + ((size_t)sh << 7)) + p;
  uint u = *bp;
  float t1 = bflo(u), t2 = bfhi(u);
  float c  = cosb[(s << 6) + p];
  float sv = sinb[(s << 6) + p];
  float o1 = t1 * c - t2 * sv;
  float o2 = t1 * sv + t2 * c;
  *bp = ((uint)f2bf(o1)) | (((uint)f2bf(o2)) << 16);
}

// ---------------- MFMA flash attention v5: 32x32 swapped-QK, in-reg softmax ---
// Per wave: 32 q-rows. S^T = mfma(K,Q): lane owns q = lane&31 entirely.
// P in registers (cvt_pk + permlane32_swap with DISTINCT values, T12).
// PV: O^T = V^T * P^T. Defer-max THR=8 (T13). DMA staging, XOR chunk swizzle
// both-sides. K single-buffer, V^T double-buffer, prefetch after barrier B.
#define OFF_V0U 8192
#define OFF_V1U 16384
#define NT (SEQ / 64)

__device__ __forceinline__ void stage_K(const ushort* __restrict__ K, ushort* SM,
                                        int w, int lane, int kb, int kvh) {
  const int r4 = lane >> 4, c16 = lane & 15;
#pragma unroll
  for (int j = 0; j < 4; ++j) {
    int rb = w * 16 + j * 4, row = rb + r4;
    int c = c16 ^ (row & 15);
    async16(K + (size_t)(kb + row) * KVDIM + kvh * HD + c * 8, &SM[rb * 128]);
  }
}
__device__ __forceinline__ void stage_V(const ushort* __restrict__ VT, ushort* SMv,
                                        int w, int lane, int kb, int kvh) {
  const int r8 = lane >> 3, c8 = lane & 7;
#pragma unroll
  for (int j = 0; j < 4; ++j) {
    int rb = w * 32 + j * 8, row = rb + r8;
    int c = c8 ^ (row & 7);
    async16(VT + (size_t)(kvh * 128 + row) * SEQ + kb + c * 8, &SMv[rb * 64]);
  }
}

__global__ __launch_bounds__(256, 2) void attn_mfma5(
    const ushort* __restrict__ Q, const ushort* __restrict__ K,
    const ushort* __restrict__ VT, ushort* __restrict__ O)
{
  __shared__ __align__(16) ushort SM[24576];   // 49152 B

  const int tid = threadIdx.x, lane = tid & 63, w = tid >> 6;
  const int l31 = lane & 31, hi = lane >> 5;
  const int kx = l31 & 15;          // row&15 for K/Q reads (rows ≡ l31 mod 32)
  const int vx = lane & 7;          // row&7 for V reads
  const int h = blockIdx.y, kvh = h >> 2;
  const int q0 = blockIdx.x * 128;

  // ---- stage Q (128 rows x 256B, swizzled chunks) via DMA into [0,16384)
  {
    const int r4 = lane >> 4, c16 = lane & 15;
#pragma unroll
    for (int j = 0; j < 8; ++j) {
      int rb = w * 32 + j * 4, row = rb + r4;
      int c = c16 ^ (row & 15);
      async16(Q + (size_t)(q0 + row) * DIM + h * HD + c * 8, &SM[rb * 128]);
    }
  }
  __syncthreads();

  // ---- Q fragments in registers: B-operand, col(q) = l31
  bf16x8 qf[8];
#pragma unroll
  for (int ks = 0; ks < 8; ++ks) {
    int cc = ((2 * ks + hi) ^ kx) << 3;
    qf[ks] = *(const bf16x8*)&SM[(w * 32 + l31) * 128 + cc];
  }
  __syncthreads();   // all Q reads done before K/V DMA lands

  // ---- prologue: stage K(0), VT(0)
  stage_K(K, SM, w, lane, 0, kvh);
  stage_V(VT, &SM[OFF_V0U], w, lane, 0, kvh);

  f32x16 oacc[4];
#pragma unroll
  for (int dt = 0; dt < 4; ++dt)
#pragma unroll
    for (int r = 0; r < 16; ++r) oacc[dt][r] = 0.f;
  float m_i = -1e30f, l_i = 0.f;

  for (int t = 0; t < NT; ++t) {
    __syncthreads();   // A: K(t)/VT(t) staging drained (vmcnt0 at barrier)

    // ---- S^T = K Q^T : 16 MFMA 32x32x16 (A = K rows, B = Q rows)
    f32x16 s0, s1;
#pragma unroll
    for (int r = 0; r < 16; ++r) { s0[r] = 0.f; s1[r] = 0.f; }
    __builtin_amdgcn_s_setprio(1);
#pragma unroll
    for (int ks = 0; ks < 8; ++ks) {
      int cc = ((2 * ks + hi) ^ kx) << 3;
      bf16x8 k0 = *(const bf16x8*)&SM[l31 * 128 + cc];
      bf16x8 k1 = *(const bf16x8*)&SM[(32 + l31) * 128 + cc];
      s0 = __builtin_amdgcn_mfma_f32_32x32x16_bf16(k0, qf[ks], s0, 0, 0, 0);
      s1 = __builtin_amdgcn_mfma_f32_32x32x16_bf16(k1, qf[ks], s1, 0, 0, 0);
    }
    __builtin_amdgcn_s_setprio(0);

    __syncthreads();   // B: all waves done reading K buffer

    // ---- prefetch next K / VT (latency hides under softmax + PV)
    if (t + 1 < NT) {
      stage_K(K, SM, w, lane, (t + 1) * 64, kvh);
      stage_V(VT, &SM[((t + 1) & 1) ? OFF_V1U : OFF_V0U], w, lane, (t + 1) * 64, kvh);
    }

    // ---- in-register online softmax (lane owns q = l31; kv split across hi)
    float tm[16];
#pragma unroll
    for (int i = 0; i < 16; ++i) tm[i] = fmaxf(s0[i], s1[i]);
#pragma unroll
    for (int d = 8; d >= 1; d >>= 1)
#pragma unroll
      for (int i = 0; i < 8; ++i) if (i < d) tm[i] = fmaxf(tm[i], tm[i + d]);
    float lm = fmaxf(tm[0], __shfl_xor(tm[0], 32));   // cross-half exchange
    float lmS = lm * SCALE;
    float mn;
    if (__any(lmS > m_i + 8.0f)) {        // rescale path (defer-max, THR=8)
      mn = fmaxf(m_i, lmS);
      float al = __expf(m_i - mn);
      m_i = mn; l_i *= al;
#pragma unroll
      for (int dt = 0; dt < 4; ++dt)
#pragma unroll
        for (int r = 0; r < 16; ++r) oacc[dt][r] *= al;
    } else mn = m_i;

    float p0[16], p1[16];
#pragma unroll
    for (int r = 0; r < 16; ++r) p0[r] = __expf(fmaf(s0[r], SCALE, -mn));
#pragma unroll
    for (int r = 0; r < 16; ++r) p1[r] = __expf(fmaf(s1[r], SCALE, -mn));
    {
      float ts[16];
#pragma unroll
      for (int i = 0; i < 16; ++i) ts[i] = p0[i] + p1[i];
#pragma unroll
      for (int d = 8; d >= 1; d >>= 1)
#pragma unroll
        for (int i = 0; i < 8; ++i) if (i < d) ts[i] += ts[i + d];
      l_i += ts[0] + __shfl_xor(ts[0], 32);           // cross-half exchange
    }

    // ---- P -> bf16 PV B-operand frags (T12): 16 cvt_pk + 8 permlane32_swap
    bf16x8 pf[4];
    {
      uint a0 = cvtpk(p0[0], p0[1]),  b0 = cvtpk(p0[4], p0[5]);   plswap(a0, b0);
      uint a1 = cvtpk(p0[2], p0[3]),  b1 = cvtpk(p0[6], p0[7]);   plswap(a1, b1);
      uint4 u0 = {a0, a1, b0, b1};  pf[0] = *(bf16x8*)&u0;
      uint a2 = cvtpk(p0[8], p0[9]),  b2 = cvtpk(p0[12], p0[13]); plswap(a2, b2);
      uint a3 = cvtpk(p0[10], p0[11]),b3 = cvtpk(p0[14], p0[15]); plswap(a3, b3);
      uint4 u1 = {a2, a3, b2, b3};  pf[1] = *(bf16x8*)&u1;
      uint a4 = cvtpk(p1[0], p1[1]),  b4 = cvtpk(p1[4], p1[5]);   plswap(a4, b4);
      uint a5 = cvtpk(p1[2], p1[3]),  b5 = cvtpk(p1[6], p1[7]);   plswap(a5, b5);
      uint4 u2 = {a4, a5, b4, b5};  pf[2] = *(bf16x8*)&u2;
      uint a6 = cvtpk(p1[8], p1[9]),  b6 = cvtpk(p1[12], p1[13]); plswap(a6, b6);
      uint a7 = cvtpk(p1[10], p1[11]),b7 = cvtpk(p1[14], p1[15]); plswap(a7, b7);
      uint4 u3 = {a6, a7, b6, b7};  pf[3] = *(bf16x8*)&u3;
    }

    // ---- PV: O^T += V^T P^T : 16 MFMA (A = V^T rows=d, B = P rows=q)
    const int vbU = (t & 1) ? OFF_V1U : OFF_V0U;
    __builtin_amdgcn_s_setprio(1);
#pragma unroll
    for (int ks = 0; ks < 4; ++ks) {
      int cc = ((2 * ks + hi) ^ vx) << 3;
#pragma unroll
      for (int dt = 0; dt < 4; ++dt) {
        bf16x8 vf = *(const bf16x8*)&SM[vbU + (dt * 32 + l31) * 64 + cc];
        oacc[dt] = __builtin_amdgcn_mfma_f32_32x32x16_bf16(vf, pf[ks], oacc[dt], 0, 0, 0);
      }
    }
    __builtin_amdgcn_s_setprio(0);
  }

  // ---- epilogue: O^T -> per-wave LDS transpose -> coalesced global store
  float linv = 1.0f / l_i;
  const int RB = w * 4096;
#pragma unroll
  for (int dt = 0; dt < 4; ++dt)
#pragma unroll
    for (int r = 0; r < 16; ++r) {
      int d = dt * 32 + (r & 3) + 8 * (r >> 2) + 4 * hi;
      SM[RB + l31 * 128 + (((d >> 3) ^ (l31 & 15)) << 3) + (d & 7)] =
          f2bf(oacc[dt][r] * linv);
    }
  {
    const int r4 = lane >> 4, c16 = lane & 15;
#pragma unroll
    for (int i = 0; i < 8; ++i) {
      int qq = i * 4 + r4;
      uint4 v = *(const uint4*)&SM[RB + qq * 128 + ((c16 ^ (qq & 15)) << 3)];
      *(uint4*)(O + (size_t)(q0 + w * 32 + qq) * DIM + h * HD + c16 * 8) = v;
    }
  }
}

// ---------------- launcher ----------------------------------------------------
extern "C" void kernel_launch(void* const* d_in, const int* in_sizes, int n_in,
                              void* d_out, int out_size, void* d_ws, size_t ws_size,
                              hipStream_t stream) {
  const float* x  = (const float*)d_in[0];
  const float* fc = (const float*)d_in[1];
  const float* fs = (const float*)d_in[2];
  const float* wq = (const float*)d_in[3];
  const float* wk = (const float*)d_in[4];
  const float* wv = (const float*)d_in[5];
  const float* wo = (const float*)d_in[6];
  float* out = (float*)d_out;

  // ws (bf16 elems): xb | wT (wqT then wkT then wvT contiguous: 6144 x 4096)
  //                  | qb | kb | vT  (vT = kb + SEQ*KVDIM)
  ushort* xb   = (ushort*)d_ws;
  ushort* wT   = xb   + (size_t)SEQ * DIM;      // 6144 x 4096 (wq | wk | wv)
  ushort* wkvT = wT   + (size_t)DIM * DIM;      // = rows 4096.. of wT
  ushort* qb   = wkvT + (size_t)2048 * DIM;
  ushort* kb   = qb   + (size_t)SEQ * DIM;
  ushort* vT   = kb   + (size_t)SEQ * KVDIM;    // 1024 x 2048
  ushort* ab   = qb;                            // attention out aliases Q

  dim3 blk(256);

  convert_f32_bf16<<<(SEQ * DIM) / 2048, blk, 0, stream>>>(x, xb);
  transpose_w<<<dim3(DIM / 32, DIM / 32), blk, 0, stream>>>(wq, wT, DIM, DIM);
  transpose_w<<<dim3(KVDIM / 32, DIM / 32), blk, 0, stream>>>(wk, wkvT, DIM, KVDIM);
  transpose_w<<<dim3(KVDIM / 32, DIM / 32), blk, 0, stream>>>(wv, wkvT + (size_t)KVDIM * DIM, DIM, KVDIM);

  // fused Q/K/V projection: N = 6144 (cols: 0..4095 Q, ..5119 K, ..6143 V^T)
  gemm_bt<<<dim3(6144 / 128, SEQ / 128), blk, 0, stream>>>(xb, wT, qb, kb, SEQ, 6144, DIM, 2);

  rope_kernel<<<(SEQ * NH * 64) / 256, blk, 0, stream>>>(qb, fc, fs, 5);
  rope_kernel<<<(SEQ * NKV * 64) / 256, blk, 0, stream>>>(kb, fc, fs, 3);

  attn_mfma5<<<dim3(SEQ / 128, NH), blk, 0, stream>>>(qb, kb, vT, ab);

  // transpose wo into the (now dead) wqT region, then output projection
  transpose_w<<<dim3(DIM / 32, DIM / 32), blk, 0, stream>>>(wo, wT, DIM, DIM);
  gemm_bt<<<dim3(DIM / 128, SEQ / 128), blk, 0, stream>>>(ab, wT, out, nullptr, SEQ, DIM, DIM, 1);
}